// Round 1
// baseline (3102.188 us; speedup 1.0000x reference)
//
#include <hip/hip_runtime.h>
#include <hip/hip_bf16.h>
#include <stdint.h>

// GATv2 3-layer network, fp32 correctness-first implementation.
// Pipeline per layer: gemm(fs), gemm(fd) -> edge logits + segment max ->
// exp + segment sum -> alpha-weighted aggregation (atomics) -> head mean + lrelu.

#define GAT_SLOPE 0.2f
#define ACT_SLOPE 0.01f

__device__ __forceinline__ unsigned f2ord(float f) {
  unsigned u = __float_as_uint(f);
  return (u & 0x80000000u) ? ~u : (u | 0x80000000u);
}
__device__ __forceinline__ float ord2f(unsigned e) {
  unsigned u = (e & 0x80000000u) ? (e & 0x7FFFFFFFu) : ~e;
  return __uint_as_float(u);
}

// ---------------- GEMM: C[N,M] = A[N,K] @ B[K,M], fp32 ----------------
// 64x64 tile, BK=16, 256 threads, 4x4 per thread. Assumes M%64==0, K%16==0
// (true for all layers: M in {512,256}, K in {512,128}); row-bounds checked.
#define BM 64
#define BN 64
#define BK 16
__global__ __launch_bounds__(256) void gemm_kernel(
    const float* __restrict__ A, const float* __restrict__ B,
    float* __restrict__ C, int Nrow, int K, int M) {
  __shared__ float As[BK][BM + 1];
  __shared__ float Bs[BK][BN + 1];
  const int bm = blockIdx.y * BM;
  const int bn = blockIdx.x * BN;
  const int tid = threadIdx.x;
  const int tr = tid / 16;  // 0..15
  const int tc = tid % 16;  // 0..15
  float acc[4][4] = {};
  for (int k0 = 0; k0 < K; k0 += BK) {
    // A tile: rows bm..bm+63, cols k0..k0+15 -> As[k][m]
    for (int t = tid; t < BM * BK; t += 256) {
      int m = t / BK, kk = t % BK;
      int row = bm + m;
      As[kk][m] = (row < Nrow) ? A[(size_t)row * K + k0 + kk] : 0.f;
    }
    // B tile: rows k0..k0+15, cols bn..bn+63 -> Bs[k][n]
    for (int t = tid; t < BK * BN; t += 256) {
      int kk = t / BN, n = t % BN;
      Bs[kk][n] = B[(size_t)(k0 + kk) * M + bn + n];
    }
    __syncthreads();
#pragma unroll
    for (int kk = 0; kk < BK; ++kk) {
      float ar[4], br[4];
#pragma unroll
      for (int i = 0; i < 4; ++i) ar[i] = As[kk][tr * 4 + i];
#pragma unroll
      for (int j = 0; j < 4; ++j) br[j] = Bs[kk][tc * 4 + j];
#pragma unroll
      for (int i = 0; i < 4; ++i)
#pragma unroll
        for (int j = 0; j < 4; ++j) acc[i][j] += ar[i] * br[j];
    }
    __syncthreads();
  }
#pragma unroll
  for (int i = 0; i < 4; ++i) {
    int row = bm + tr * 4 + i;
    if (row >= Nrow) continue;
#pragma unroll
    for (int j = 0; j < 4; ++j)
      C[(size_t)row * M + bn + tc * 4 + j] = acc[i][j];
  }
}

// ------------- edge logits + segment max (one wave per edge-head) -------------
// logit[e,h] = sum_d attn[h,d] * lrelu(fs[src,h,d] + fd[dst,h,d], 0.2)
__global__ __launch_bounds__(256) void edge_logits_kernel(
    const float* __restrict__ fs, const float* __restrict__ fd,
    const int* __restrict__ src, const int* __restrict__ dst,
    const float* __restrict__ attn, float* __restrict__ logit,
    unsigned* __restrict__ mEnc, int E, int D) {
  const int wid = blockIdx.x * 4 + (threadIdx.x >> 6);
  const int lane = threadIdx.x & 63;
  if (wid >= E * 4) return;
  const int e = wid >> 2;
  const int h = wid & 3;
  const int sn = src[e];
  const int dn = dst[e];
  const int HD = 4 * D;
  const float* fsp = fs + (size_t)sn * HD + h * D;
  const float* fdp = fd + (size_t)dn * HD + h * D;
  const float* ap = attn + h * D;
  float acc = 0.f;
  for (int i = lane; i < D; i += 64) {
    float v = fsp[i] + fdp[i];
    v = v > 0.f ? v : v * GAT_SLOPE;
    acc += ap[i] * v;
  }
#pragma unroll
  for (int off = 32; off; off >>= 1) acc += __shfl_down(acc, off, 64);
  if (lane == 0) {
    logit[(size_t)e * 4 + h] = acc;
    atomicMax(&mEnc[(size_t)dn * 4 + h], f2ord(acc));
  }
}

// ------------- exp(logit - m[dst]) in-place + segment sum -------------
__global__ __launch_bounds__(256) void edge_exp_kernel(
    float* __restrict__ a, const unsigned* __restrict__ mEnc,
    const int* __restrict__ dst, float* __restrict__ ssum, int E) {
  const int i = blockIdx.x * blockDim.x + threadIdx.x;
  if (i >= E * 4) return;
  const int e = i >> 2;
  const int h = i & 3;
  const int dn = dst[e];
  const float m = ord2f(mEnc[dn * 4 + h]);
  const float v = __expf(a[i] - m);
  a[i] = v;
  atomicAdd(&ssum[dn * 4 + h], v);
}

// ------------- agg[dst] += (a/s[dst]) * fs[src]  (one block per edge) -------------
__global__ __launch_bounds__(256) void edge_aggregate_kernel(
    const float* __restrict__ fs, const int* __restrict__ src,
    const int* __restrict__ dst, const float* __restrict__ a,
    const float* __restrict__ ssum, float* __restrict__ agg, int D) {
  const int e = blockIdx.x;
  const int HD = 4 * D;
  const int sn = src[e];
  const int dn = dst[e];
  const float* fsp = fs + (size_t)sn * HD;
  float* op = agg + (size_t)dn * HD;
  for (int i = threadIdx.x; i < HD; i += blockDim.x) {
    const int h = i / D;
    const float alpha = a[(size_t)e * 4 + h] / ssum[(size_t)dn * 4 + h];
    atomicAdd(&op[i], alpha * fsp[i]);
  }
}

// ------------- h_out[n,d] = lrelu( mean_h(agg[n,h,d] + b[h,d]), 0.01 ) -------------
__global__ __launch_bounds__(256) void head_mean_kernel(
    const float* __restrict__ agg, const float* __restrict__ b,
    float* __restrict__ hout, int N, int D) {
  const int i = blockIdx.x * blockDim.x + threadIdx.x;
  if (i >= N * D) return;
  const int n = i / D;
  const int d = i % D;
  const float* ap = agg + (size_t)n * 4 * D;
  float acc = 0.f;
#pragma unroll
  for (int h = 0; h < 4; ++h) acc += ap[h * D + d] + b[h * D + d];
  acc *= 0.25f;
  hout[i] = acc > 0.f ? acc : acc * ACT_SLOPE;
}

// ------------- out[d] = mean_n h[n,d]  (D=64) -------------
__global__ __launch_bounds__(64) void final_mean_kernel(
    const float* __restrict__ h, float* __restrict__ out, int N) {
  const int d = threadIdx.x;  // 64 threads
  float acc = 0.f;
  for (int n = blockIdx.x; n < N; n += gridDim.x) acc += h[(size_t)n * 64 + d];
  atomicAdd(&out[d], acc / (float)N);
}

// ------------------------------------------------------------------
static void run_layer(const float* h_in, int K, int D, const float* Wl,
                      const float* Wr, const float* attn, const float* b,
                      const int* src, const int* dst, int N, int E, float* fs,
                      float* fd, float* agg, float* logit, unsigned* mEnc,
                      float* ssum, float* h_out, hipStream_t stream) {
  const int HD = 4 * D;
  hipMemsetAsync(agg, 0, (size_t)N * HD * sizeof(float), stream);
  hipMemsetAsync(mEnc, 0, (size_t)N * 4 * sizeof(unsigned), stream);
  hipMemsetAsync(ssum, 0, (size_t)N * 4 * sizeof(float), stream);
  dim3 gg(HD / BN, (N + BM - 1) / BM);
  gemm_kernel<<<gg, 256, 0, stream>>>(h_in, Wl, fs, N, K, HD);
  gemm_kernel<<<gg, 256, 0, stream>>>(h_in, Wr, fd, N, K, HD);
  const int totalWaves = E * 4;
  edge_logits_kernel<<<(totalWaves + 3) / 4, 256, 0, stream>>>(
      fs, fd, src, dst, attn, logit, mEnc, E, D);
  edge_exp_kernel<<<(E * 4 + 255) / 256, 256, 0, stream>>>(logit, mEnc, dst,
                                                           ssum, E);
  edge_aggregate_kernel<<<E, 256, 0, stream>>>(fs, src, dst, logit, ssum, agg,
                                               D);
  head_mean_kernel<<<((size_t)N * D + 255) / 256, 256, 0, stream>>>(agg, b,
                                                                    h_out, N, D);
}

extern "C" void kernel_launch(void* const* d_in, const int* in_sizes, int n_in,
                              void* d_out, int out_size, void* d_ws,
                              size_t ws_size, hipStream_t stream) {
  const float* n_feat = (const float*)d_in[0];
  const int* src = (const int*)d_in[1];
  const int* dst = (const int*)d_in[2];
  const float* Wl0 = (const float*)d_in[3];
  const float* Wr0 = (const float*)d_in[4];
  const float* attn0 = (const float*)d_in[5];
  const float* b0 = (const float*)d_in[6];
  const float* Wl1 = (const float*)d_in[7];
  const float* Wr1 = (const float*)d_in[8];
  const float* attn1 = (const float*)d_in[9];
  const float* b1 = (const float*)d_in[10];
  const float* Wl2 = (const float*)d_in[11];
  const float* Wr2 = (const float*)d_in[12];
  const float* attn2 = (const float*)d_in[13];
  const float* b2 = (const float*)d_in[14];

  const int N = in_sizes[0] / 512;  // 20000
  const int E = in_sizes[1];        // 320000

  // workspace layout (floats)
  float* ws = (float*)d_ws;
  size_t o = 0;
  float* fs = ws + o;     o += (size_t)N * 512;
  float* fd = ws + o;     o += (size_t)N * 512;
  float* agg = ws + o;    o += (size_t)N * 512;
  float* logit = ws + o;  o += (size_t)E * 4;   // reused in-place for exp numerators
  unsigned* mEnc = (unsigned*)(ws + o); o += (size_t)N * 4;
  float* ssum = ws + o;   o += (size_t)N * 4;
  float* h1 = ws + o;     o += (size_t)N * 128;
  float* h2 = ws + o;     o += (size_t)N * 128;

  // layer 0: 512 -> 4x128
  run_layer(n_feat, 512, 128, Wl0, Wr0, attn0, b0, src, dst, N, E, fs, fd, agg,
            logit, mEnc, ssum, h1, stream);
  // layer 1: 128 -> 4x128
  run_layer(h1, 128, 128, Wl1, Wr1, attn1, b1, src, dst, N, E, fs, fd, agg,
            logit, mEnc, ssum, h2, stream);
  // layer 2: 128 -> 4x64
  run_layer(h2, 128, 64, Wl2, Wr2, attn2, b2, src, dst, N, E, fs, fd, agg,
            logit, mEnc, ssum, h1, stream);

  // final per-graph mean readout -> [1, 64]
  hipMemsetAsync(d_out, 0, 64 * sizeof(float), stream);
  final_mean_kernel<<<256, 64, 0, stream>>>(h1, (float*)d_out, N);
}

// Round 2
// 1144.016 us; speedup vs baseline: 2.7117x; 2.7117x over previous
//
#include <hip/hip_runtime.h>
#include <hip/hip_bf16.h>
#include <stdint.h>

// GATv2 3-layer network. Round 1: CSR-by-dst + fused per-node online-softmax
// attention kernel (no atomics in hot path). GEMMs still fp32 vector.

#define GAT_SLOPE 0.2f
#define ACT_SLOPE 0.01f

// ---------------- GEMM: C[N,M] = A[N,K] @ B[K,M], fp32 ----------------
#define BM 64
#define BN 64
#define BK 16
__global__ __launch_bounds__(256) void gemm_kernel(
    const float* __restrict__ A, const float* __restrict__ B,
    float* __restrict__ C, int Nrow, int K, int M) {
  __shared__ float As[BK][BM + 1];
  __shared__ float Bs[BK][BN + 1];
  const int bm = blockIdx.y * BM;
  const int bn = blockIdx.x * BN;
  const int tid = threadIdx.x;
  const int tr = tid / 16;
  const int tc = tid % 16;
  float acc[4][4] = {};
  for (int k0 = 0; k0 < K; k0 += BK) {
    for (int t = tid; t < BM * BK; t += 256) {
      int m = t / BK, kk = t % BK;
      int row = bm + m;
      As[kk][m] = (row < Nrow) ? A[(size_t)row * K + k0 + kk] : 0.f;
    }
    for (int t = tid; t < BK * BN; t += 256) {
      int kk = t / BN, n = t % BN;
      Bs[kk][n] = B[(size_t)(k0 + kk) * M + bn + n];
    }
    __syncthreads();
#pragma unroll
    for (int kk = 0; kk < BK; ++kk) {
      float ar[4], br[4];
#pragma unroll
      for (int i = 0; i < 4; ++i) ar[i] = As[kk][tr * 4 + i];
#pragma unroll
      for (int j = 0; j < 4; ++j) br[j] = Bs[kk][tc * 4 + j];
#pragma unroll
      for (int i = 0; i < 4; ++i)
#pragma unroll
        for (int j = 0; j < 4; ++j) acc[i][j] += ar[i] * br[j];
    }
    __syncthreads();
  }
#pragma unroll
  for (int i = 0; i < 4; ++i) {
    int row = bm + tr * 4 + i;
    if (row >= Nrow) continue;
#pragma unroll
    for (int j = 0; j < 4; ++j)
      C[(size_t)row * M + bn + tc * 4 + j] = acc[i][j];
  }
}

// ---------------- CSR build ----------------
__global__ __launch_bounds__(256) void hist_kernel(const int* __restrict__ dst,
                                                   int* __restrict__ counts,
                                                   int E) {
  int e = blockIdx.x * 256 + threadIdx.x;
  if (e < E) atomicAdd(&counts[dst[e]], 1);
}

__global__ __launch_bounds__(256) void scan_kernel(
    const int* __restrict__ counts, int* __restrict__ rowptr,
    int* __restrict__ cursor, int N) {
  __shared__ int sums[256];
  const int t = threadIdx.x;
  const int C = (N + 255) / 256;
  const int lo = t * C;
  const int hi = min(lo + C, N);
  int s = 0;
  for (int i = lo; i < hi; ++i) s += counts[i];
  sums[t] = s;
  __syncthreads();
  for (int off = 1; off < 256; off <<= 1) {
    int v = (t >= off) ? sums[t - off] : 0;
    __syncthreads();
    sums[t] += v;
    __syncthreads();
  }
  int run = (t == 0) ? 0 : sums[t - 1];
  for (int i = lo; i < hi; ++i) {
    rowptr[i] = run;
    cursor[i] = run;
    run += counts[i];
  }
  if (t == 255) rowptr[N] = run;
}

__global__ __launch_bounds__(256) void scatter_kernel(
    const int* __restrict__ dst, int* __restrict__ cursor,
    int* __restrict__ eidx, int E) {
  int e = blockIdx.x * 256 + threadIdx.x;
  if (e < E) {
    int p = atomicAdd(&cursor[dst[e]], 1);
    eidx[p] = e;
  }
}

// ---------------- fused per-node GATv2 attention ----------------
// One wave (64 threads) per dst node. Online softmax over incoming edges.
// Computes logits, softmax, weighted aggregation, bias, head-mean, lrelu.
// D = head dim (128 or 64); HD = 4*D; R = HD/64 floats per lane.
// Lane l covers features [l*R, l*R+R) -> head h = l>>4.
template <int D>
__global__ __launch_bounds__(64) void node_attn_kernel(
    const float* __restrict__ fs, const float* __restrict__ fd,
    const int* __restrict__ rowptr, const int* __restrict__ eidx,
    const int* __restrict__ src, const float* __restrict__ attn,
    const float* __restrict__ bias, float* __restrict__ hout, int N) {
  constexpr int HD = 4 * D;
  constexpr int R = HD / 64;
  const int v = blockIdx.x;
  if (v >= N) return;
  const int lane = threadIdx.x;

  float fdr[R], ar[R];
  const float* fdv = fd + (size_t)v * HD + lane * R;
#pragma unroll
  for (int i = 0; i < R; ++i) fdr[i] = fdv[i];
#pragma unroll
  for (int i = 0; i < R; ++i) ar[i] = attn[lane * R + i];

  float m = -INFINITY, l = 0.f;
  float O[R];
#pragma unroll
  for (int i = 0; i < R; ++i) O[i] = 0.f;

  const int e0 = rowptr[v];
  const int e1 = rowptr[v + 1];
  for (int k = e0; k < e1; ++k) {
    const int e = eidx[k];
    const int s = src[e];
    const float* fsp = fs + (size_t)s * HD + lane * R;
    float fsr[R];
#pragma unroll
    for (int i = 0; i < R; ++i) fsr[i] = fsp[i];
    // per-head logit: dot(attn_h, lrelu(fs+fd, 0.2)) reduced over 16 lanes
    float part = 0.f;
#pragma unroll
    for (int i = 0; i < R; ++i) {
      float x = fsr[i] + fdr[i];
      x = x > 0.f ? x : x * GAT_SLOPE;
      part += ar[i] * x;
    }
    part += __shfl_xor(part, 1, 64);
    part += __shfl_xor(part, 2, 64);
    part += __shfl_xor(part, 4, 64);
    part += __shfl_xor(part, 8, 64);
    const float logit = part;  // all 16 lanes of a head hold the head's logit
    // online softmax update
    const float mnew = fmaxf(m, logit);
    const float scale = __expf(m - mnew);  // exp(-inf)=0 on first edge
    const float p = __expf(logit - mnew);
    l = l * scale + p;
#pragma unroll
    for (int i = 0; i < R; ++i) O[i] = O[i] * scale + p * fsr[i];
    m = mnew;
  }

  const float inv = (l > 0.f) ? 1.f / l : 0.f;
#pragma unroll
  for (int i = 0; i < R; ++i) O[i] = O[i] * inv + bias[lane * R + i];
  // mean over heads: combine lanes l, l^16, l^32, l^48 (same d, diff head)
#pragma unroll
  for (int i = 0; i < R; ++i) {
    O[i] += __shfl_xor(O[i], 16, 64);
    O[i] += __shfl_xor(O[i], 32, 64);
    float x = O[i] * 0.25f;
    O[i] = x > 0.f ? x : x * ACT_SLOPE;
  }
  if (lane < 16) {
    float* op = hout + (size_t)v * D + lane * R;
#pragma unroll
    for (int i = 0; i < R; ++i) op[i] = O[i];
  }
}

// ------------- out[d] = mean_n h[n,d]  (D=64) -------------
__global__ __launch_bounds__(64) void final_mean_kernel(
    const float* __restrict__ h, float* __restrict__ out, int N) {
  const int d = threadIdx.x;
  float acc = 0.f;
  for (int n = blockIdx.x; n < N; n += gridDim.x) acc += h[(size_t)n * 64 + d];
  atomicAdd(&out[d], acc / (float)N);
}

// ------------------------------------------------------------------
extern "C" void kernel_launch(void* const* d_in, const int* in_sizes, int n_in,
                              void* d_out, int out_size, void* d_ws,
                              size_t ws_size, hipStream_t stream) {
  const float* n_feat = (const float*)d_in[0];
  const int* src = (const int*)d_in[1];
  const int* dst = (const int*)d_in[2];
  const float* Wl0 = (const float*)d_in[3];
  const float* Wr0 = (const float*)d_in[4];
  const float* attn0 = (const float*)d_in[5];
  const float* b0 = (const float*)d_in[6];
  const float* Wl1 = (const float*)d_in[7];
  const float* Wr1 = (const float*)d_in[8];
  const float* attn1 = (const float*)d_in[9];
  const float* b1 = (const float*)d_in[10];
  const float* Wl2 = (const float*)d_in[11];
  const float* Wr2 = (const float*)d_in[12];
  const float* attn2 = (const float*)d_in[13];
  const float* b2 = (const float*)d_in[14];

  const int N = in_sizes[0] / 512;  // 20000
  const int E = in_sizes[1];        // 320000

  // workspace layout (floats / ints)
  float* ws = (float*)d_ws;
  size_t o = 0;
  float* fs = ws + o;   o += (size_t)N * 512;
  float* fd = ws + o;   o += (size_t)N * 512;
  float* h1 = ws + o;   o += (size_t)N * 128;
  float* h2 = ws + o;   o += (size_t)N * 128;
  int* counts = (int*)(ws + o);  o += N;
  int* rowptr = (int*)(ws + o);  o += N + 1;
  int* cursor = (int*)(ws + o);  o += N;
  int* eidx   = (int*)(ws + o);  o += E;

  // ---- CSR by dst (rebuilt every call; no state carried) ----
  hipMemsetAsync(counts, 0, (size_t)N * sizeof(int), stream);
  hist_kernel<<<(E + 255) / 256, 256, 0, stream>>>(dst, counts, E);
  scan_kernel<<<1, 256, 0, stream>>>(counts, rowptr, cursor, N);
  scatter_kernel<<<(E + 255) / 256, 256, 0, stream>>>(dst, cursor, eidx, E);

  // ---- layer 0: 512 -> 4x128 ----
  {
    dim3 gg(512 / BN, (N + BM - 1) / BM);
    gemm_kernel<<<gg, 256, 0, stream>>>(n_feat, Wl0, fs, N, 512, 512);
    gemm_kernel<<<gg, 256, 0, stream>>>(n_feat, Wr0, fd, N, 512, 512);
    node_attn_kernel<128><<<N, 64, 0, stream>>>(fs, fd, rowptr, eidx, src,
                                                attn0, b0, h1, N);
  }
  // ---- layer 1: 128 -> 4x128 ----
  {
    dim3 gg(512 / BN, (N + BM - 1) / BM);
    gemm_kernel<<<gg, 256, 0, stream>>>(h1, Wl1, fs, N, 128, 512);
    gemm_kernel<<<gg, 256, 0, stream>>>(h1, Wr1, fd, N, 128, 512);
    node_attn_kernel<128><<<N, 64, 0, stream>>>(fs, fd, rowptr, eidx, src,
                                                attn1, b1, h2, N);
  }
  // ---- layer 2: 128 -> 4x64 ----
  {
    dim3 gg(256 / BN, (N + BM - 1) / BM);
    gemm_kernel<<<gg, 256, 0, stream>>>(h2, Wl2, fs, N, 128, 256);
    gemm_kernel<<<gg, 256, 0, stream>>>(h2, Wr2, fd, N, 128, 256);
    node_attn_kernel<64><<<N, 64, 0, stream>>>(fs, fd, rowptr, eidx, src,
                                               attn2, b2, h1, N);
  }

  // ---- final per-graph mean readout -> [1, 64] ----
  hipMemsetAsync(d_out, 0, 64 * sizeof(float), stream);
  final_mean_kernel<<<256, 64, 0, stream>>>(h1, (float*)d_out, N);
}

// Round 3
// 675.640 us; speedup vs baseline: 4.5915x; 1.6932x over previous
//
#include <hip/hip_runtime.h>
#include <hip/hip_bf16.h>
#include <stdint.h>

// GATv2 3-layer network. Round 2: GEMMs moved to bf16 MFMA with 3-term
// split-precision (Ahi*Bhi + Alo*Bhi + Ahi*Blo), fp32-grade accuracy.
// Edge phase: CSR-by-dst fused online-softmax attention (round 1).

#define GAT_SLOPE 0.2f
#define ACT_SLOPE 0.01f

typedef short short8 __attribute__((ext_vector_type(8)));
typedef float floatx4 __attribute__((ext_vector_type(4)));
typedef unsigned int uint4_t __attribute__((ext_vector_type(4)));

// ---------------- fp32 -> (hi, lo) bf16 split ----------------
__device__ __forceinline__ unsigned short bf16_rn(float x) {
  unsigned u = __float_as_uint(x);
  unsigned r = (u + 0x7FFFu + ((u >> 16) & 1u)) >> 16;
  return (unsigned short)r;
}
__device__ __forceinline__ float bf16_to_f(unsigned short h) {
  return __uint_as_float(((unsigned)h) << 16);
}

__global__ __launch_bounds__(256) void split_kernel(
    const float* __restrict__ in, unsigned short* __restrict__ hi,
    unsigned short* __restrict__ lo, int n) {
  for (int i = blockIdx.x * 256 + threadIdx.x; i < n; i += gridDim.x * 256) {
    float a = in[i];
    unsigned short h = bf16_rn(a);
    hi[i] = h;
    lo[i] = bf16_rn(a - bf16_to_f(h));
  }
}

// W [K][M] -> Wt_hi/lo [M][K] (bf16)
__global__ __launch_bounds__(256) void transpose_split_kernel(
    const float* __restrict__ W, unsigned short* __restrict__ hi,
    unsigned short* __restrict__ lo, int K, int M) {
  int i = blockIdx.x * 256 + threadIdx.x;
  if (i >= K * M) return;
  int k = i / M, m = i % M;
  float a = W[i];
  unsigned short h = bf16_rn(a);
  hi[(size_t)m * K + k] = h;
  lo[(size_t)m * K + k] = bf16_rn(a - bf16_to_f(h));
}

// ---------------- split-bf16 MFMA GEMM ----------------
// C[N,M] = A[N,K] @ B[K,M], A given as hi/lo bf16 [N,K], B as hi/lo bf16 [M,K]
// (pre-transposed). 128x128 tile, 256 threads (4 waves), 16x16x32 MFMA.
#define TM 128
#define TN 128
#define TK 32
#define APAD 8  // pad rows to 40 bf16 elems (80 B) -> conflict-free
#define ROWP (TK + APAD)

__global__ __launch_bounds__(256) void gemm_mfma_kernel(
    const unsigned short* __restrict__ Ahi, const unsigned short* __restrict__ Alo,
    const unsigned short* __restrict__ Bhi, const unsigned short* __restrict__ Blo,
    float* __restrict__ C, int Nrow, int K, int M) {
  __shared__ __align__(16) unsigned short AsH[TM * ROWP];
  __shared__ __align__(16) unsigned short AsL[TM * ROWP];
  __shared__ __align__(16) unsigned short BsH[TN * ROWP];
  __shared__ __align__(16) unsigned short BsL[TN * ROWP];

  const int bm = blockIdx.y * TM;
  const int bn = blockIdx.x * TN;
  const int tid = threadIdx.x;
  const int w = tid >> 6;
  const int lane = tid & 63;
  const int wr = w >> 1;
  const int wc = w & 1;
  const int quad = lane >> 4;
  const int lr = lane & 15;

  floatx4 acc[4][4];
#pragma unroll
  for (int i = 0; i < 4; ++i)
#pragma unroll
    for (int j = 0; j < 4; ++j) acc[i][j] = (floatx4){0.f, 0.f, 0.f, 0.f};

  const int KT = K / TK;
  for (int kt = 0; kt < KT; ++kt) {
    const int k0 = kt * TK;
    // stage A (hi/lo): 128 rows x 32 elems = 512 chunks of 8 bf16 (16B)
#pragma unroll
    for (int it = 0; it < 2; ++it) {
      int c = tid + it * 256;
      int row = c >> 2, off = c & 3;
      int grow = bm + row;
      uint4_t va = {0u, 0u, 0u, 0u}, vb = {0u, 0u, 0u, 0u};
      if (grow < Nrow) {
        size_t g = (size_t)grow * K + k0 + off * 8;
        va = *(const uint4_t*)(Ahi + g);
        vb = *(const uint4_t*)(Alo + g);
      }
      int l = row * ROWP + off * 8;
      *(uint4_t*)(AsH + l) = va;
      *(uint4_t*)(AsL + l) = vb;
    }
    // stage B (hi/lo): Bt is [M][K]; cols bn..bn+127
#pragma unroll
    for (int it = 0; it < 2; ++it) {
      int c = tid + it * 256;
      int n = c >> 2, off = c & 3;
      size_t g = (size_t)(bn + n) * K + k0 + off * 8;
      int l = n * ROWP + off * 8;
      *(uint4_t*)(BsH + l) = *(const uint4_t*)(Bhi + g);
      *(uint4_t*)(BsL + l) = *(const uint4_t*)(Blo + g);
    }
    __syncthreads();

    short8 ah[4], al[4], bh[4], bl[4];
#pragma unroll
    for (int i = 0; i < 4; ++i) {
      int row = wr * 64 + i * 16 + lr;
      int l = row * ROWP + quad * 8;
      ah[i] = *(const short8*)(AsH + l);
      al[i] = *(const short8*)(AsL + l);
    }
#pragma unroll
    for (int j = 0; j < 4; ++j) {
      int col = wc * 64 + j * 16 + lr;
      int l = col * ROWP + quad * 8;
      bh[j] = *(const short8*)(BsH + l);
      bl[j] = *(const short8*)(BsL + l);
    }
#pragma unroll
    for (int i = 0; i < 4; ++i)
#pragma unroll
      for (int j = 0; j < 4; ++j) {
        acc[i][j] = __builtin_amdgcn_mfma_f32_16x16x32_bf16(ah[i], bh[j],
                                                            acc[i][j], 0, 0, 0);
        acc[i][j] = __builtin_amdgcn_mfma_f32_16x16x32_bf16(al[i], bh[j],
                                                            acc[i][j], 0, 0, 0);
        acc[i][j] = __builtin_amdgcn_mfma_f32_16x16x32_bf16(ah[i], bl[j],
                                                            acc[i][j], 0, 0, 0);
      }
    __syncthreads();
  }

  // epilogue: C/D layout col=lane&15, row=quad*4+reg
#pragma unroll
  for (int i = 0; i < 4; ++i) {
#pragma unroll
    for (int r = 0; r < 4; ++r) {
      int row = bm + wr * 64 + i * 16 + quad * 4 + r;
      if (row >= Nrow) continue;
#pragma unroll
      for (int j = 0; j < 4; ++j) {
        int col = bn + wc * 64 + j * 16 + lr;
        C[(size_t)row * M + col] = acc[i][j][r];
      }
    }
  }
}

// ---------------- CSR build ----------------
__global__ __launch_bounds__(256) void hist_kernel(const int* __restrict__ dst,
                                                   int* __restrict__ counts,
                                                   int E) {
  int e = blockIdx.x * 256 + threadIdx.x;
  if (e < E) atomicAdd(&counts[dst[e]], 1);
}

__global__ __launch_bounds__(256) void scan_kernel(
    const int* __restrict__ counts, int* __restrict__ rowptr,
    int* __restrict__ cursor, int N) {
  __shared__ int sums[256];
  const int t = threadIdx.x;
  const int C = (N + 255) / 256;
  const int lo = t * C;
  const int hi = min(lo + C, N);
  int s = 0;
  for (int i = lo; i < hi; ++i) s += counts[i];
  sums[t] = s;
  __syncthreads();
  for (int off = 1; off < 256; off <<= 1) {
    int v = (t >= off) ? sums[t - off] : 0;
    __syncthreads();
    sums[t] += v;
    __syncthreads();
  }
  int run = (t == 0) ? 0 : sums[t - 1];
  for (int i = lo; i < hi; ++i) {
    rowptr[i] = run;
    cursor[i] = run;
    run += counts[i];
  }
  if (t == 255) rowptr[N] = run;
}

__global__ __launch_bounds__(256) void scatter_kernel(
    const int* __restrict__ dst, int* __restrict__ cursor,
    int* __restrict__ eidx, int E) {
  int e = blockIdx.x * 256 + threadIdx.x;
  if (e < E) {
    int p = atomicAdd(&cursor[dst[e]], 1);
    eidx[p] = e;
  }
}

// ---------------- fused per-node GATv2 attention ----------------
template <int D>
__global__ __launch_bounds__(64) void node_attn_kernel(
    const float* __restrict__ fs, const float* __restrict__ fd,
    const int* __restrict__ rowptr, const int* __restrict__ eidx,
    const int* __restrict__ src, const float* __restrict__ attn,
    const float* __restrict__ bias, float* __restrict__ hout, int N) {
  constexpr int HD = 4 * D;
  constexpr int R = HD / 64;
  const int v = blockIdx.x;
  if (v >= N) return;
  const int lane = threadIdx.x;

  float fdr[R], ar[R];
  const float* fdv = fd + (size_t)v * HD + lane * R;
#pragma unroll
  for (int i = 0; i < R; ++i) fdr[i] = fdv[i];
#pragma unroll
  for (int i = 0; i < R; ++i) ar[i] = attn[lane * R + i];

  float m = -INFINITY, l = 0.f;
  float O[R];
#pragma unroll
  for (int i = 0; i < R; ++i) O[i] = 0.f;

  const int e0 = rowptr[v];
  const int e1 = rowptr[v + 1];
  for (int k = e0; k < e1; ++k) {
    const int e = eidx[k];
    const int s = src[e];
    const float* fsp = fs + (size_t)s * HD + lane * R;
    float fsr[R];
#pragma unroll
    for (int i = 0; i < R; ++i) fsr[i] = fsp[i];
    float part = 0.f;
#pragma unroll
    for (int i = 0; i < R; ++i) {
      float x = fsr[i] + fdr[i];
      x = x > 0.f ? x : x * GAT_SLOPE;
      part += ar[i] * x;
    }
    part += __shfl_xor(part, 1, 64);
    part += __shfl_xor(part, 2, 64);
    part += __shfl_xor(part, 4, 64);
    part += __shfl_xor(part, 8, 64);
    const float logit = part;
    const float mnew = fmaxf(m, logit);
    const float scale = __expf(m - mnew);
    const float p = __expf(logit - mnew);
    l = l * scale + p;
#pragma unroll
    for (int i = 0; i < R; ++i) O[i] = O[i] * scale + p * fsr[i];
    m = mnew;
  }

  const float inv = (l > 0.f) ? 1.f / l : 0.f;
#pragma unroll
  for (int i = 0; i < R; ++i) O[i] = O[i] * inv + bias[lane * R + i];
#pragma unroll
  for (int i = 0; i < R; ++i) {
    O[i] += __shfl_xor(O[i], 16, 64);
    O[i] += __shfl_xor(O[i], 32, 64);
    float x = O[i] * 0.25f;
    O[i] = x > 0.f ? x : x * ACT_SLOPE;
  }
  if (lane < 16) {
    float* op = hout + (size_t)v * D + lane * R;
#pragma unroll
    for (int i = 0; i < R; ++i) op[i] = O[i];
  }
}

// ------------- out[d] = mean_n h[n,d] -------------
__global__ __launch_bounds__(64) void final_mean_kernel(
    const float* __restrict__ h, float* __restrict__ out, int N) {
  const int d = threadIdx.x;
  float acc = 0.f;
  for (int n = blockIdx.x; n < N; n += gridDim.x) acc += h[(size_t)n * 64 + d];
  atomicAdd(&out[d], acc / (float)N);
}

// ------------------------------------------------------------------
extern "C" void kernel_launch(void* const* d_in, const int* in_sizes, int n_in,
                              void* d_out, int out_size, void* d_ws,
                              size_t ws_size, hipStream_t stream) {
  const float* n_feat = (const float*)d_in[0];
  const int* src = (const int*)d_in[1];
  const int* dst = (const int*)d_in[2];
  const float* Wl[3] = {(const float*)d_in[3], (const float*)d_in[7],
                        (const float*)d_in[11]};
  const float* Wr[3] = {(const float*)d_in[4], (const float*)d_in[8],
                        (const float*)d_in[12]};
  const float* attn[3] = {(const float*)d_in[5], (const float*)d_in[9],
                          (const float*)d_in[13]};
  const float* bias[3] = {(const float*)d_in[6], (const float*)d_in[10],
                          (const float*)d_in[14]};

  const int N = in_sizes[0] / 512;  // 20000
  const int E = in_sizes[1];        // 320000
  const int Kdim[3] = {512, 128, 128};
  const int Mdim[3] = {512, 512, 256};

  // workspace layout
  char* ws = (char*)d_ws;
  size_t o = 0;
  auto alloc = [&](size_t bytes) {
    void* p = ws + o;
    o += (bytes + 15) & ~(size_t)15;
    return p;
  };
  float* fs = (float*)alloc((size_t)N * 512 * 4);
  float* fd = (float*)alloc((size_t)N * 512 * 4);
  float* h1 = (float*)alloc((size_t)N * 128 * 4);
  float* h2 = (float*)alloc((size_t)N * 128 * 4);
  unsigned short* Ahi = (unsigned short*)alloc((size_t)N * 512 * 2);
  unsigned short* Alo = (unsigned short*)alloc((size_t)N * 512 * 2);
  unsigned short *WlT_h[3], *WlT_l[3], *WrT_h[3], *WrT_l[3];
  for (int L = 0; L < 3; ++L) {
    size_t sz = (size_t)Kdim[L] * Mdim[L] * 2;
    WlT_h[L] = (unsigned short*)alloc(sz);
    WlT_l[L] = (unsigned short*)alloc(sz);
    WrT_h[L] = (unsigned short*)alloc(sz);
    WrT_l[L] = (unsigned short*)alloc(sz);
  }
  int* counts = (int*)alloc((size_t)N * 4);
  int* rowptr = (int*)alloc((size_t)(N + 1) * 4);
  int* cursor = (int*)alloc((size_t)N * 4);
  int* eidx = (int*)alloc((size_t)E * 4);

  // ---- weight transpose+split (once per call) ----
  for (int L = 0; L < 3; ++L) {
    int KM = Kdim[L] * Mdim[L];
    transpose_split_kernel<<<(KM + 255) / 256, 256, 0, stream>>>(
        Wl[L], WlT_h[L], WlT_l[L], Kdim[L], Mdim[L]);
    transpose_split_kernel<<<(KM + 255) / 256, 256, 0, stream>>>(
        Wr[L], WrT_h[L], WrT_l[L], Kdim[L], Mdim[L]);
  }

  // ---- CSR by dst ----
  hipMemsetAsync(counts, 0, (size_t)N * sizeof(int), stream);
  hist_kernel<<<(E + 255) / 256, 256, 0, stream>>>(dst, counts, E);
  scan_kernel<<<1, 256, 0, stream>>>(counts, rowptr, cursor, N);
  scatter_kernel<<<(E + 255) / 256, 256, 0, stream>>>(dst, cursor, eidx, E);

  const float* layer_in[3] = {n_feat, h1, h2};
  float* layer_out[3] = {h1, h2, h1};

  for (int L = 0; L < 3; ++L) {
    const int K = Kdim[L], M = Mdim[L];
    int nA = N * K;
    split_kernel<<<1024, 256, 0, stream>>>(layer_in[L], Ahi, Alo, nA);
    dim3 gg(M / TN, (N + TM - 1) / TM);
    gemm_mfma_kernel<<<gg, 256, 0, stream>>>(Ahi, Alo, WlT_h[L], WlT_l[L], fs,
                                             N, K, M);
    gemm_mfma_kernel<<<gg, 256, 0, stream>>>(Ahi, Alo, WrT_h[L], WrT_l[L], fd,
                                             N, K, M);
    if (M == 512) {
      node_attn_kernel<128><<<N, 64, 0, stream>>>(fs, fd, rowptr, eidx, src,
                                                  attn[L], bias[L],
                                                  layer_out[L], N);
    } else {
      node_attn_kernel<64><<<N, 64, 0, stream>>>(fs, fd, rowptr, eidx, src,
                                                 attn[L], bias[L],
                                                 layer_out[L], N);
    }
  }

  // ---- final per-graph mean readout -> [1, 64] ----
  hipMemsetAsync(d_out, 0, 64 * sizeof(float), stream);
  final_mean_kernel<<<256, 64, 0, stream>>>(h1, (float*)d_out, N);
}

// Round 4
// 538.053 us; speedup vs baseline: 5.7656x; 1.2557x over previous
//
#include <hip/hip_runtime.h>
#include <hip/hip_bf16.h>
#include <stdint.h>

// GATv2 3-layer network. Round 3: fp16 fs/fd (written by GEMM epilogue),
// CSR stores src directly, edge loop unrolled x2 (paired online-softmax),
// dual-B fused GEMM (Wl+Wr in one dispatch). GEMM compute: split-bf16 MFMA.

#define GAT_SLOPE 0.2f
#define ACT_SLOPE 0.01f

typedef short short8 __attribute__((ext_vector_type(8)));
typedef float floatx4 __attribute__((ext_vector_type(4)));
typedef unsigned int uint4_t __attribute__((ext_vector_type(4)));
typedef _Float16 half8 __attribute__((ext_vector_type(8)));
typedef _Float16 half4 __attribute__((ext_vector_type(4)));

// ---------------- fp32 -> (hi, lo) bf16 split ----------------
__device__ __forceinline__ unsigned short bf16_rn(float x) {
  unsigned u = __float_as_uint(x);
  unsigned r = (u + 0x7FFFu + ((u >> 16) & 1u)) >> 16;
  return (unsigned short)r;
}
__device__ __forceinline__ float bf16_to_f(unsigned short h) {
  return __uint_as_float(((unsigned)h) << 16);
}

__global__ __launch_bounds__(256) void split_kernel(
    const float* __restrict__ in, unsigned short* __restrict__ hi,
    unsigned short* __restrict__ lo, int n) {
  for (int i = blockIdx.x * 256 + threadIdx.x; i < n; i += gridDim.x * 256) {
    float a = in[i];
    unsigned short h = bf16_rn(a);
    hi[i] = h;
    lo[i] = bf16_rn(a - bf16_to_f(h));
  }
}

// W [K][M] -> Wt_hi/lo [M][K] (bf16)
__global__ __launch_bounds__(256) void transpose_split_kernel(
    const float* __restrict__ W, unsigned short* __restrict__ hi,
    unsigned short* __restrict__ lo, int K, int M) {
  int i = blockIdx.x * 256 + threadIdx.x;
  if (i >= K * M) return;
  int k = i / M, m = i % M;
  float a = W[i];
  unsigned short h = bf16_rn(a);
  hi[(size_t)m * K + k] = h;
  lo[(size_t)m * K + k] = bf16_rn(a - bf16_to_f(h));
}

// ---------------- split-bf16 MFMA GEMM, dual-B, fp16 output ----------------
// C0[N,M] = A@B0, C1[N,M] = A@B1. A hi/lo bf16 [N,K]; B hi/lo bf16 [M,K].
// 128x128 tile, 256 threads (4 waves), 16x16x32 MFMA, 3-term split product.
#define TM 128
#define TN 128
#define TK 32
#define APAD 8
#define ROWP (TK + APAD)

__global__ __launch_bounds__(256) void gemm_mfma_dual_kernel(
    const unsigned short* __restrict__ Ahi, const unsigned short* __restrict__ Alo,
    const unsigned short* __restrict__ B0hi, const unsigned short* __restrict__ B0lo,
    const unsigned short* __restrict__ B1hi, const unsigned short* __restrict__ B1lo,
    _Float16* __restrict__ C0, _Float16* __restrict__ C1, int Nrow, int K,
    int M) {
  __shared__ __align__(16) unsigned short AsH[TM * ROWP];
  __shared__ __align__(16) unsigned short AsL[TM * ROWP];
  __shared__ __align__(16) unsigned short BsH[TN * ROWP];
  __shared__ __align__(16) unsigned short BsL[TN * ROWP];

  const int nb = M / TN;
  const bool second = (int)blockIdx.x >= nb;
  const unsigned short* Bhi = second ? B1hi : B0hi;
  const unsigned short* Blo = second ? B1lo : B0lo;
  _Float16* C = second ? C1 : C0;
  const int bn = (second ? blockIdx.x - nb : blockIdx.x) * TN;
  const int bm = blockIdx.y * TM;
  const int tid = threadIdx.x;
  const int w = tid >> 6;
  const int lane = tid & 63;
  const int wr = w >> 1;
  const int wc = w & 1;
  const int quad = lane >> 4;
  const int lr = lane & 15;

  floatx4 acc[4][4];
#pragma unroll
  for (int i = 0; i < 4; ++i)
#pragma unroll
    for (int j = 0; j < 4; ++j) acc[i][j] = (floatx4){0.f, 0.f, 0.f, 0.f};

  const int KT = K / TK;
  for (int kt = 0; kt < KT; ++kt) {
    const int k0 = kt * TK;
#pragma unroll
    for (int it = 0; it < 2; ++it) {
      int c = tid + it * 256;
      int row = c >> 2, off = c & 3;
      int grow = bm + row;
      uint4_t va = {0u, 0u, 0u, 0u}, vb = {0u, 0u, 0u, 0u};
      if (grow < Nrow) {
        size_t g = (size_t)grow * K + k0 + off * 8;
        va = *(const uint4_t*)(Ahi + g);
        vb = *(const uint4_t*)(Alo + g);
      }
      int l = row * ROWP + off * 8;
      *(uint4_t*)(AsH + l) = va;
      *(uint4_t*)(AsL + l) = vb;
    }
#pragma unroll
    for (int it = 0; it < 2; ++it) {
      int c = tid + it * 256;
      int n = c >> 2, off = c & 3;
      size_t g = (size_t)(bn + n) * K + k0 + off * 8;
      int l = n * ROWP + off * 8;
      *(uint4_t*)(BsH + l) = *(const uint4_t*)(Bhi + g);
      *(uint4_t*)(BsL + l) = *(const uint4_t*)(Blo + g);
    }
    __syncthreads();

    short8 ah[4], al[4], bh[4], bl[4];
#pragma unroll
    for (int i = 0; i < 4; ++i) {
      int row = wr * 64 + i * 16 + lr;
      int l = row * ROWP + quad * 8;
      ah[i] = *(const short8*)(AsH + l);
      al[i] = *(const short8*)(AsL + l);
    }
#pragma unroll
    for (int j = 0; j < 4; ++j) {
      int col = wc * 64 + j * 16 + lr;
      int l = col * ROWP + quad * 8;
      bh[j] = *(const short8*)(BsH + l);
      bl[j] = *(const short8*)(BsL + l);
    }
#pragma unroll
    for (int i = 0; i < 4; ++i)
#pragma unroll
      for (int j = 0; j < 4; ++j) {
        acc[i][j] = __builtin_amdgcn_mfma_f32_16x16x32_bf16(ah[i], bh[j],
                                                            acc[i][j], 0, 0, 0);
        acc[i][j] = __builtin_amdgcn_mfma_f32_16x16x32_bf16(al[i], bh[j],
                                                            acc[i][j], 0, 0, 0);
        acc[i][j] = __builtin_amdgcn_mfma_f32_16x16x32_bf16(ah[i], bl[j],
                                                            acc[i][j], 0, 0, 0);
      }
    __syncthreads();
  }

#pragma unroll
  for (int i = 0; i < 4; ++i) {
#pragma unroll
    for (int r = 0; r < 4; ++r) {
      int row = bm + wr * 64 + i * 16 + quad * 4 + r;
      if (row >= Nrow) continue;
#pragma unroll
      for (int j = 0; j < 4; ++j) {
        int col = bn + wc * 64 + j * 16 + lr;
        C[(size_t)row * M + col] = (_Float16)acc[i][j][r];
      }
    }
  }
}

// ---------------- CSR build (stores src directly) ----------------
__global__ __launch_bounds__(256) void hist_kernel(const int* __restrict__ dst,
                                                   int* __restrict__ counts,
                                                   int E) {
  int e = blockIdx.x * 256 + threadIdx.x;
  if (e < E) atomicAdd(&counts[dst[e]], 1);
}

__global__ __launch_bounds__(256) void scan_kernel(
    const int* __restrict__ counts, int* __restrict__ rowptr,
    int* __restrict__ cursor, int N) {
  __shared__ int sums[256];
  const int t = threadIdx.x;
  const int C = (N + 255) / 256;
  const int lo = t * C;
  const int hi = min(lo + C, N);
  int s = 0;
  for (int i = lo; i < hi; ++i) s += counts[i];
  sums[t] = s;
  __syncthreads();
  for (int off = 1; off < 256; off <<= 1) {
    int v = (t >= off) ? sums[t - off] : 0;
    __syncthreads();
    sums[t] += v;
    __syncthreads();
  }
  int run = (t == 0) ? 0 : sums[t - 1];
  for (int i = lo; i < hi; ++i) {
    rowptr[i] = run;
    cursor[i] = run;
    run += counts[i];
  }
  if (t == 255) rowptr[N] = run;
}

__global__ __launch_bounds__(256) void scatter_kernel(
    const int* __restrict__ src, const int* __restrict__ dst,
    int* __restrict__ cursor, int* __restrict__ csrc, int E) {
  int e = blockIdx.x * 256 + threadIdx.x;
  if (e < E) {
    int p = atomicAdd(&cursor[dst[e]], 1);
    csrc[p] = src[e];
  }
}

// ---------------- fused per-node GATv2 attention (fp16 features) ----------------
// One wave per dst node, 4 nodes per block. Edge loop unrolled x2.
template <int D>
__global__ __launch_bounds__(256) void node_attn_kernel(
    const _Float16* __restrict__ fs, const _Float16* __restrict__ fd,
    const int* __restrict__ rowptr, const int* __restrict__ csrc,
    const float* __restrict__ attn, const float* __restrict__ bias,
    float* __restrict__ hout, int N) {
  constexpr int HD = 4 * D;
  constexpr int R = HD / 64;
  typedef _Float16 halfR __attribute__((ext_vector_type(R)));
  const int v = blockIdx.x * 4 + (threadIdx.x >> 6);
  if (v >= N) return;
  const int lane = threadIdx.x & 63;

  float fdr[R], ar[R];
  {
    halfR t = *(const halfR*)(fd + (size_t)v * HD + lane * R);
#pragma unroll
    for (int i = 0; i < R; ++i) fdr[i] = (float)t[i];
  }
#pragma unroll
  for (int i = 0; i < R; ++i) ar[i] = attn[lane * R + i];

  float m = -INFINITY, l = 0.f;
  float O[R];
#pragma unroll
  for (int i = 0; i < R; ++i) O[i] = 0.f;

  const int e0 = rowptr[v];
  const int e1 = rowptr[v + 1];
  int k = e0;
  for (; k + 1 < e1; k += 2) {
    const int s0 = csrc[k];
    const int s1 = csrc[k + 1];
    halfR t0 = *(const halfR*)(fs + (size_t)s0 * HD + lane * R);
    halfR t1 = *(const halfR*)(fs + (size_t)s1 * HD + lane * R);
    float f0[R], f1[R];
#pragma unroll
    for (int i = 0; i < R; ++i) { f0[i] = (float)t0[i]; f1[i] = (float)t1[i]; }
    float p0 = 0.f, p1 = 0.f;
#pragma unroll
    for (int i = 0; i < R; ++i) {
      float x0 = f0[i] + fdr[i];
      float x1 = f1[i] + fdr[i];
      x0 = x0 > 0.f ? x0 : x0 * GAT_SLOPE;
      x1 = x1 > 0.f ? x1 : x1 * GAT_SLOPE;
      p0 += ar[i] * x0;
      p1 += ar[i] * x1;
    }
#pragma unroll
    for (int off = 1; off <= 8; off <<= 1) {
      p0 += __shfl_xor(p0, off, 64);
      p1 += __shfl_xor(p1, off, 64);
    }
    // pairwise softmax merge
    const float mp = fmaxf(p0, p1);
    const float w0 = __expf(p0 - mp);
    const float w1 = __expf(p1 - mp);
    const float mnew = fmaxf(m, mp);
    const float sc = __expf(m - mnew);
    const float sp = __expf(mp - mnew);
    l = l * sc + (w0 + w1) * sp;
#pragma unroll
    for (int i = 0; i < R; ++i)
      O[i] = O[i] * sc + (w0 * f0[i] + w1 * f1[i]) * sp;
    m = mnew;
  }
  if (k < e1) {
    const int s0 = csrc[k];
    halfR t0 = *(const halfR*)(fs + (size_t)s0 * HD + lane * R);
    float f0[R];
#pragma unroll
    for (int i = 0; i < R; ++i) f0[i] = (float)t0[i];
    float p0 = 0.f;
#pragma unroll
    for (int i = 0; i < R; ++i) {
      float x = f0[i] + fdr[i];
      x = x > 0.f ? x : x * GAT_SLOPE;
      p0 += ar[i] * x;
    }
#pragma unroll
    for (int off = 1; off <= 8; off <<= 1) p0 += __shfl_xor(p0, off, 64);
    const float mnew = fmaxf(m, p0);
    const float sc = __expf(m - mnew);
    const float p = __expf(p0 - mnew);
    l = l * sc + p;
#pragma unroll
    for (int i = 0; i < R; ++i) O[i] = O[i] * sc + p * f0[i];
    m = mnew;
  }

  const float inv = (l > 0.f) ? 1.f / l : 0.f;
#pragma unroll
  for (int i = 0; i < R; ++i) O[i] = O[i] * inv + bias[lane * R + i];
#pragma unroll
  for (int i = 0; i < R; ++i) {
    O[i] += __shfl_xor(O[i], 16, 64);
    O[i] += __shfl_xor(O[i], 32, 64);
    float x = O[i] * 0.25f;
    O[i] = x > 0.f ? x : x * ACT_SLOPE;
  }
  if (lane < 16) {
    float* op = hout + (size_t)v * D + lane * R;
#pragma unroll
    for (int i = 0; i < R; ++i) op[i] = O[i];
  }
}

// ------------- out[d] = mean_n h[n,d] -------------
__global__ __launch_bounds__(64) void final_mean_kernel(
    const float* __restrict__ h, float* __restrict__ out, int N) {
  const int d = threadIdx.x;
  float acc = 0.f;
  for (int n = blockIdx.x; n < N; n += gridDim.x) acc += h[(size_t)n * 64 + d];
  atomicAdd(&out[d], acc / (float)N);
}

// ------------------------------------------------------------------
extern "C" void kernel_launch(void* const* d_in, const int* in_sizes, int n_in,
                              void* d_out, int out_size, void* d_ws,
                              size_t ws_size, hipStream_t stream) {
  const float* n_feat = (const float*)d_in[0];
  const int* src = (const int*)d_in[1];
  const int* dst = (const int*)d_in[2];
  const float* Wl[3] = {(const float*)d_in[3], (const float*)d_in[7],
                        (const float*)d_in[11]};
  const float* Wr[3] = {(const float*)d_in[4], (const float*)d_in[8],
                        (const float*)d_in[12]};
  const float* attn[3] = {(const float*)d_in[5], (const float*)d_in[9],
                          (const float*)d_in[13]};
  const float* bias[3] = {(const float*)d_in[6], (const float*)d_in[10],
                          (const float*)d_in[14]};

  const int N = in_sizes[0] / 512;  // 20000
  const int E = in_sizes[1];        // 320000
  const int Kdim[3] = {512, 128, 128};
  const int Mdim[3] = {512, 512, 256};

  char* ws = (char*)d_ws;
  size_t o = 0;
  auto alloc = [&](size_t bytes) {
    void* p = ws + o;
    o += (bytes + 15) & ~(size_t)15;
    return p;
  };
  _Float16* fs = (_Float16*)alloc((size_t)N * 512 * 2);
  _Float16* fd = (_Float16*)alloc((size_t)N * 512 * 2);
  float* h1 = (float*)alloc((size_t)N * 128 * 4);
  float* h2 = (float*)alloc((size_t)N * 128 * 4);
  unsigned short* Ahi = (unsigned short*)alloc((size_t)N * 512 * 2);
  unsigned short* Alo = (unsigned short*)alloc((size_t)N * 512 * 2);
  unsigned short *WlT_h[3], *WlT_l[3], *WrT_h[3], *WrT_l[3];
  for (int L = 0; L < 3; ++L) {
    size_t sz = (size_t)Kdim[L] * Mdim[L] * 2;
    WlT_h[L] = (unsigned short*)alloc(sz);
    WlT_l[L] = (unsigned short*)alloc(sz);
    WrT_h[L] = (unsigned short*)alloc(sz);
    WrT_l[L] = (unsigned short*)alloc(sz);
  }
  int* counts = (int*)alloc((size_t)N * 4);
  int* rowptr = (int*)alloc((size_t)(N + 1) * 4);
  int* cursor = (int*)alloc((size_t)N * 4);
  int* csrc = (int*)alloc((size_t)E * 4);

  // ---- weight transpose+split ----
  for (int L = 0; L < 3; ++L) {
    int KM = Kdim[L] * Mdim[L];
    transpose_split_kernel<<<(KM + 255) / 256, 256, 0, stream>>>(
        Wl[L], WlT_h[L], WlT_l[L], Kdim[L], Mdim[L]);
    transpose_split_kernel<<<(KM + 255) / 256, 256, 0, stream>>>(
        Wr[L], WrT_h[L], WrT_l[L], Kdim[L], Mdim[L]);
  }

  // ---- CSR by dst ----
  hipMemsetAsync(counts, 0, (size_t)N * sizeof(int), stream);
  hist_kernel<<<(E + 255) / 256, 256, 0, stream>>>(dst, counts, E);
  scan_kernel<<<1, 256, 0, stream>>>(counts, rowptr, cursor, N);
  scatter_kernel<<<(E + 255) / 256, 256, 0, stream>>>(src, dst, cursor, csrc,
                                                      E);

  const float* layer_in[3] = {n_feat, h1, h2};
  float* layer_out[3] = {h1, h2, h1};

  for (int L = 0; L < 3; ++L) {
    const int K = Kdim[L], M = Mdim[L];
    split_kernel<<<1024, 256, 0, stream>>>(layer_in[L], Ahi, Alo, N * K);
    dim3 gg(2 * M / TN, (N + TM - 1) / TM);
    gemm_mfma_dual_kernel<<<gg, 256, 0, stream>>>(
        Ahi, Alo, WlT_h[L], WlT_l[L], WrT_h[L], WrT_l[L], fs, fd, N, K, M);
    if (M == 512) {
      node_attn_kernel<128><<<(N + 3) / 4, 256, 0, stream>>>(
          fs, fd, rowptr, csrc, attn[L], bias[L], layer_out[L], N);
    } else {
      node_attn_kernel<64><<<(N + 3) / 4, 256, 0, stream>>>(
          fs, fd, rowptr, csrc, attn[L], bias[L], layer_out[L], N);
    }
  }

  hipMemsetAsync(d_out, 0, 64 * sizeof(float), stream);
  final_mean_kernel<<<256, 64, 0, stream>>>(h1, (float*)d_out, N);
}

// Round 5
// 509.720 us; speedup vs baseline: 6.0861x; 1.0556x over previous
//
#include <hip/hip_runtime.h>
#include <hip/hip_bf16.h>
#include <stdint.h>

// GATv2 3-layer network. Round 4:
//  - GEMM staging via __builtin_amdgcn_global_load_lds (width=16), unpadded
//    TK=32 rows (64B row stride -> balanced bank pattern for ds_read_b128).
//  - Merged weight transpose (1 launch), next-layer bf16 hi/lo split fused
//    into node_attn epilogue (kills 2 split launches).
//  - GEMM compute: 3-term split-bf16 MFMA; fs/fd fp16; CSR attn unchanged.

#define GAT_SLOPE 0.2f
#define ACT_SLOPE 0.01f

typedef short short8 __attribute__((ext_vector_type(8)));
typedef float floatx4 __attribute__((ext_vector_type(4)));

// ---------------- fp32 -> (hi, lo) bf16 split helpers ----------------
__device__ __forceinline__ unsigned short bf16_rn(float x) {
  unsigned u = __float_as_uint(x);
  unsigned r = (u + 0x7FFFu + ((u >> 16) & 1u)) >> 16;
  return (unsigned short)r;
}
__device__ __forceinline__ float bf16_to_f(unsigned short h) {
  return __uint_as_float(((unsigned)h) << 16);
}

__global__ __launch_bounds__(256) void split_kernel(
    const float* __restrict__ in, unsigned short* __restrict__ hi,
    unsigned short* __restrict__ lo, int n) {
  for (int i = blockIdx.x * 256 + threadIdx.x; i < n; i += gridDim.x * 256) {
    float a = in[i];
    unsigned short h = bf16_rn(a);
    hi[i] = h;
    lo[i] = bf16_rn(a - bf16_to_f(h));
  }
}

// ---------------- merged weight transpose+split (all 6 matrices) ----------------
struct TransDesc {
  const float* src;
  unsigned short* hi;
  unsigned short* lo;
  int K, M, off;
};
struct TransArgs {
  TransDesc d[6];
  int total;
};

__global__ __launch_bounds__(256) void transpose_all_kernel(TransArgs ta) {
  int i = blockIdx.x * 256 + threadIdx.x;
  if (i >= ta.total) return;
  int q = 0;
#pragma unroll
  for (int j = 1; j < 6; ++j)
    if (i >= ta.d[j].off) q = j;
  int local = i - ta.d[q].off;
  int K = ta.d[q].K, M = ta.d[q].M;
  int k = local / M, m = local % M;
  float a = ta.d[q].src[local];
  unsigned short h = bf16_rn(a);
  ta.d[q].hi[(size_t)m * K + k] = h;
  ta.d[q].lo[(size_t)m * K + k] = bf16_rn(a - bf16_to_f(h));
}

// ---------------- async global -> LDS (16B per lane, wave-uniform LDS base) ----
__device__ __forceinline__ void gload_lds16(const unsigned short* g,
                                            unsigned short* l) {
  __builtin_amdgcn_global_load_lds(
      (__attribute__((address_space(1))) unsigned int*)g,
      (__attribute__((address_space(3))) unsigned int*)l, 16, 0, 0);
}

// ---------------- split-bf16 MFMA GEMM, dual-B, fp16 output ----------------
// C0[N,M]=A@B0, C1[N,M]=A@B1. A hi/lo bf16 [N,K]; B hi/lo bf16 [M,K].
// 128x128 tile, 256 threads (4 waves), TK=32, 16x16x32 MFMA, 3-term split.
#define TM 128
#define TN 128
#define TK 32

__global__ __launch_bounds__(256) void gemm_mfma_dual_kernel(
    const unsigned short* __restrict__ Ahi, const unsigned short* __restrict__ Alo,
    const unsigned short* __restrict__ B0hi, const unsigned short* __restrict__ B0lo,
    const unsigned short* __restrict__ B1hi, const unsigned short* __restrict__ B1lo,
    _Float16* __restrict__ C0, _Float16* __restrict__ C1, int Nrow, int K,
    int M) {
  __shared__ __align__(16) unsigned short AsH[TM * TK];
  __shared__ __align__(16) unsigned short AsL[TM * TK];
  __shared__ __align__(16) unsigned short BsH[TN * TK];
  __shared__ __align__(16) unsigned short BsL[TN * TK];

  const int nb = M / TN;
  const bool second = (int)blockIdx.x >= nb;
  const unsigned short* Bhi = second ? B1hi : B0hi;
  const unsigned short* Blo = second ? B1lo : B0lo;
  _Float16* C = second ? C1 : C0;
  const int bn = (second ? blockIdx.x - nb : blockIdx.x) * TN;
  const int bm = blockIdx.y * TM;
  const int tid = threadIdx.x;
  const int w = tid >> 6;
  const int lane = tid & 63;
  const int wr = w >> 1;
  const int wc = w & 1;
  const int quad = lane >> 4;
  const int lr = lane & 15;

  // staging: wave w stages rows [w*32, w*32+32) of each of the 4 arrays,
  // as 2 instructions of 16 rows (64 lanes x 16B = 16 rows x 64B).
  const int lrow = lane >> 2;        // 0..15 within a 16-row chunk
  const int loff = (lane & 3) * 8;   // element offset within row

  floatx4 acc[4][4];
#pragma unroll
  for (int i = 0; i < 4; ++i)
#pragma unroll
    for (int j = 0; j < 4; ++j) acc[i][j] = (floatx4){0.f, 0.f, 0.f, 0.f};

  const int KT = K / TK;
  for (int kt = 0; kt < KT; ++kt) {
    const int k0 = kt * TK;
#pragma unroll
    for (int half = 0; half < 2; ++half) {
      const int r0 = w * 32 + half * 16;
      // A rows (clamped to avoid OOB; clamped rows' outputs are discarded)
      int ga = bm + r0 + lrow;
      if (ga >= Nrow) ga = Nrow - 1;
      const size_t aoff = (size_t)ga * K + k0 + loff;
      gload_lds16(Ahi + aoff, AsH + r0 * TK);
      gload_lds16(Alo + aoff, AsL + r0 * TK);
      // B cols (always in range: M % 128 == 0)
      const size_t boff = (size_t)(bn + r0 + lrow) * K + k0 + loff;
      gload_lds16(Bhi + boff, BsH + r0 * TK);
      gload_lds16(Blo + boff, BsL + r0 * TK);
    }
    __syncthreads();

    short8 ah[4], al[4], bh[4], bl[4];
#pragma unroll
    for (int i = 0; i < 4; ++i) {
      int row = wr * 64 + i * 16 + lr;
      int l = row * TK + quad * 8;
      ah[i] = *(const short8*)(AsH + l);
      al[i] = *(const short8*)(AsL + l);
    }
#pragma unroll
    for (int j = 0; j < 4; ++j) {
      int col = wc * 64 + j * 16 + lr;
      int l = col * TK + quad * 8;
      bh[j] = *(const short8*)(BsH + l);
      bl[j] = *(const short8*)(BsL + l);
    }
#pragma unroll
    for (int i = 0; i < 4; ++i)
#pragma unroll
      for (int j = 0; j < 4; ++j) {
        acc[i][j] = __builtin_amdgcn_mfma_f32_16x16x32_bf16(ah[i], bh[j],
                                                            acc[i][j], 0, 0, 0);
        acc[i][j] = __builtin_amdgcn_mfma_f32_16x16x32_bf16(al[i], bh[j],
                                                            acc[i][j], 0, 0, 0);
        acc[i][j] = __builtin_amdgcn_mfma_f32_16x16x32_bf16(ah[i], bl[j],
                                                            acc[i][j], 0, 0, 0);
      }
    __syncthreads();
  }

  // epilogue: C/D layout col=lane&15, row=quad*4+reg
#pragma unroll
  for (int i = 0; i < 4; ++i) {
#pragma unroll
    for (int r = 0; r < 4; ++r) {
      int row = bm + wr * 64 + i * 16 + quad * 4 + r;
      if (row >= Nrow) continue;
#pragma unroll
      for (int j = 0; j < 4; ++j) {
        int col = bn + wc * 64 + j * 16 + lr;
        C[(size_t)row * M + col] = (_Float16)acc[i][j][r];
      }
    }
  }
}

// ---------------- CSR build (stores src directly) ----------------
__global__ __launch_bounds__(256) void hist_kernel(const int* __restrict__ dst,
                                                   int* __restrict__ counts,
                                                   int E) {
  int e = blockIdx.x * 256 + threadIdx.x;
  if (e < E) atomicAdd(&counts[dst[e]], 1);
}

__global__ __launch_bounds__(256) void scan_kernel(
    const int* __restrict__ counts, int* __restrict__ rowptr,
    int* __restrict__ cursor, int N) {
  __shared__ int sums[256];
  const int t = threadIdx.x;
  const int C = (N + 255) / 256;
  const int lo = t * C;
  const int hi = min(lo + C, N);
  int s = 0;
  for (int i = lo; i < hi; ++i) s += counts[i];
  sums[t] = s;
  __syncthreads();
  for (int off = 1; off < 256; off <<= 1) {
    int v = (t >= off) ? sums[t - off] : 0;
    __syncthreads();
    sums[t] += v;
    __syncthreads();
  }
  int run = (t == 0) ? 0 : sums[t - 1];
  for (int i = lo; i < hi; ++i) {
    rowptr[i] = run;
    cursor[i] = run;
    run += counts[i];
  }
  if (t == 255) rowptr[N] = run;
}

__global__ __launch_bounds__(256) void scatter_kernel(
    const int* __restrict__ src, const int* __restrict__ dst,
    int* __restrict__ cursor, int* __restrict__ csrc, int E) {
  int e = blockIdx.x * 256 + threadIdx.x;
  if (e < E) {
    int p = atomicAdd(&cursor[dst[e]], 1);
    csrc[p] = src[e];
  }
}

// ---------------- fused per-node GATv2 attention (fp16 features) ----------------
// One wave per dst node, 4 nodes per block. Edge loop unrolled x2.
// Epilogue writes either fp32 h (hout) and/or bf16 hi/lo split (next layer A).
template <int D>
__global__ __launch_bounds__(256) void node_attn_kernel(
    const _Float16* __restrict__ fs, const _Float16* __restrict__ fd,
    const int* __restrict__ rowptr, const int* __restrict__ csrc,
    const float* __restrict__ attn, const float* __restrict__ bias,
    float* __restrict__ hout, unsigned short* __restrict__ ohi,
    unsigned short* __restrict__ olo, int N) {
  constexpr int HD = 4 * D;
  constexpr int R = HD / 64;
  typedef _Float16 halfR __attribute__((ext_vector_type(R)));
  const int v = blockIdx.x * 4 + (threadIdx.x >> 6);
  if (v >= N) return;
  const int lane = threadIdx.x & 63;

  float fdr[R], ar[R];
  {
    halfR t = *(const halfR*)(fd + (size_t)v * HD + lane * R);
#pragma unroll
    for (int i = 0; i < R; ++i) fdr[i] = (float)t[i];
  }
#pragma unroll
  for (int i = 0; i < R; ++i) ar[i] = attn[lane * R + i];

  float m = -INFINITY, l = 0.f;
  float O[R];
#pragma unroll
  for (int i = 0; i < R; ++i) O[i] = 0.f;

  const int e0 = rowptr[v];
  const int e1 = rowptr[v + 1];
  int k = e0;
  for (; k + 1 < e1; k += 2) {
    const int s0 = csrc[k];
    const int s1 = csrc[k + 1];
    halfR t0 = *(const halfR*)(fs + (size_t)s0 * HD + lane * R);
    halfR t1 = *(const halfR*)(fs + (size_t)s1 * HD + lane * R);
    float f0[R], f1[R];
#pragma unroll
    for (int i = 0; i < R; ++i) { f0[i] = (float)t0[i]; f1[i] = (float)t1[i]; }
    float p0 = 0.f, p1 = 0.f;
#pragma unroll
    for (int i = 0; i < R; ++i) {
      float x0 = f0[i] + fdr[i];
      float x1 = f1[i] + fdr[i];
      x0 = x0 > 0.f ? x0 : x0 * GAT_SLOPE;
      x1 = x1 > 0.f ? x1 : x1 * GAT_SLOPE;
      p0 += ar[i] * x0;
      p1 += ar[i] * x1;
    }
#pragma unroll
    for (int off = 1; off <= 8; off <<= 1) {
      p0 += __shfl_xor(p0, off, 64);
      p1 += __shfl_xor(p1, off, 64);
    }
    const float mp = fmaxf(p0, p1);
    const float w0 = __expf(p0 - mp);
    const float w1 = __expf(p1 - mp);
    const float mnew = fmaxf(m, mp);
    const float sc = __expf(m - mnew);
    const float sp = __expf(mp - mnew);
    l = l * sc + (w0 + w1) * sp;
#pragma unroll
    for (int i = 0; i < R; ++i)
      O[i] = O[i] * sc + (w0 * f0[i] + w1 * f1[i]) * sp;
    m = mnew;
  }
  if (k < e1) {
    const int s0 = csrc[k];
    halfR t0 = *(const halfR*)(fs + (size_t)s0 * HD + lane * R);
    float f0[R];
#pragma unroll
    for (int i = 0; i < R; ++i) f0[i] = (float)t0[i];
    float p0 = 0.f;
#pragma unroll
    for (int i = 0; i < R; ++i) {
      float x = f0[i] + fdr[i];
      x = x > 0.f ? x : x * GAT_SLOPE;
      p0 += ar[i] * x;
    }
#pragma unroll
    for (int off = 1; off <= 8; off <<= 1) p0 += __shfl_xor(p0, off, 64);
    const float mnew = fmaxf(m, p0);
    const float sc = __expf(m - mnew);
    const float p = __expf(p0 - mnew);
    l = l * sc + p;
#pragma unroll
    for (int i = 0; i < R; ++i) O[i] = O[i] * sc + p * f0[i];
    m = mnew;
  }

  const float inv = (l > 0.f) ? 1.f / l : 0.f;
#pragma unroll
  for (int i = 0; i < R; ++i) O[i] = O[i] * inv + bias[lane * R + i];
#pragma unroll
  for (int i = 0; i < R; ++i) {
    O[i] += __shfl_xor(O[i], 16, 64);
    O[i] += __shfl_xor(O[i], 32, 64);
    float x = O[i] * 0.25f;
    O[i] = x > 0.f ? x : x * ACT_SLOPE;
  }
  if (lane < 16) {
    const size_t base = (size_t)v * D + lane * R;
    if (hout) {
#pragma unroll
      for (int i = 0; i < R; ++i) hout[base + i] = O[i];
    }
    if (ohi) {
#pragma unroll
      for (int i = 0; i < R; ++i) {
        unsigned short h = bf16_rn(O[i]);
        ohi[base + i] = h;
        olo[base + i] = bf16_rn(O[i] - bf16_to_f(h));
      }
    }
  }
}

// ------------- out[d] = mean_n h[n,d] -------------
__global__ __launch_bounds__(64) void final_mean_kernel(
    const float* __restrict__ h, float* __restrict__ out, int N) {
  const int d = threadIdx.x;
  float acc = 0.f;
  for (int n = blockIdx.x; n < N; n += gridDim.x) acc += h[(size_t)n * 64 + d];
  atomicAdd(&out[d], acc / (float)N);
}

// ------------------------------------------------------------------
extern "C" void kernel_launch(void* const* d_in, const int* in_sizes, int n_in,
                              void* d_out, int out_size, void* d_ws,
                              size_t ws_size, hipStream_t stream) {
  const float* n_feat = (const float*)d_in[0];
  const int* src = (const int*)d_in[1];
  const int* dst = (const int*)d_in[2];
  const float* Wl[3] = {(const float*)d_in[3], (const float*)d_in[7],
                        (const float*)d_in[11]};
  const float* Wr[3] = {(const float*)d_in[4], (const float*)d_in[8],
                        (const float*)d_in[12]};
  const float* attn[3] = {(const float*)d_in[5], (const float*)d_in[9],
                          (const float*)d_in[13]};
  const float* bias[3] = {(const float*)d_in[6], (const float*)d_in[10],
                          (const float*)d_in[14]};

  const int N = in_sizes[0] / 512;  // 20000
  const int E = in_sizes[1];        // 320000
  const int Kdim[3] = {512, 128, 128};
  const int Mdim[3] = {512, 512, 256};

  char* ws = (char*)d_ws;
  size_t o = 0;
  auto alloc = [&](size_t bytes) {
    void* p = ws + o;
    o += (bytes + 15) & ~(size_t)15;
    return p;
  };
  _Float16* fs = (_Float16*)alloc((size_t)N * 512 * 2);
  _Float16* fd = (_Float16*)alloc((size_t)N * 512 * 2);
  unsigned short* A0hi = (unsigned short*)alloc((size_t)N * 512 * 2);
  unsigned short* A0lo = (unsigned short*)alloc((size_t)N * 512 * 2);
  unsigned short* h1hi = (unsigned short*)alloc((size_t)N * 128 * 2);
  unsigned short* h1lo = (unsigned short*)alloc((size_t)N * 128 * 2);
  unsigned short* h2hi = (unsigned short*)alloc((size_t)N * 128 * 2);
  unsigned short* h2lo = (unsigned short*)alloc((size_t)N * 128 * 2);
  float* hfin = (float*)alloc((size_t)N * 64 * 4);
  unsigned short *WlT_h[3], *WlT_l[3], *WrT_h[3], *WrT_l[3];
  for (int L = 0; L < 3; ++L) {
    size_t sz = (size_t)Kdim[L] * Mdim[L] * 2;
    WlT_h[L] = (unsigned short*)alloc(sz);
    WlT_l[L] = (unsigned short*)alloc(sz);
    WrT_h[L] = (unsigned short*)alloc(sz);
    WrT_l[L] = (unsigned short*)alloc(sz);
  }
  int* counts = (int*)alloc((size_t)N * 4);
  int* rowptr = (int*)alloc((size_t)(N + 1) * 4);
  int* cursor = (int*)alloc((size_t)N * 4);
  int* csrc = (int*)alloc((size_t)E * 4);

  // ---- merged weight transpose+split (1 launch) ----
  {
    TransArgs ta;
    int off = 0;
    for (int L = 0; L < 3; ++L) {
      ta.d[2 * L] = {Wl[L], WlT_h[L], WlT_l[L], Kdim[L], Mdim[L], off};
      off += Kdim[L] * Mdim[L];
      ta.d[2 * L + 1] = {Wr[L], WrT_h[L], WrT_l[L], Kdim[L], Mdim[L], off};
      off += Kdim[L] * Mdim[L];
    }
    ta.total = off;
    transpose_all_kernel<<<(ta.total + 255) / 256, 256, 0, stream>>>(ta);
  }

  // ---- split layer-0 input ----
  split_kernel<<<1024, 256, 0, stream>>>(n_feat, A0hi, A0lo, N * 512);

  // ---- CSR by dst ----
  hipMemsetAsync(counts, 0, (size_t)N * sizeof(int), stream);
  hist_kernel<<<(E + 255) / 256, 256, 0, stream>>>(dst, counts, E);
  scan_kernel<<<1, 256, 0, stream>>>(counts, rowptr, cursor, N);
  scatter_kernel<<<(E + 255) / 256, 256, 0, stream>>>(src, dst, cursor, csrc,
                                                      E);

  const unsigned short* Ah[3] = {A0hi, h1hi, h2hi};
  const unsigned short* Al[3] = {A0lo, h1lo, h2lo};

  for (int L = 0; L < 3; ++L) {
    const int K = Kdim[L], M = Mdim[L];
    dim3 gg(2 * M / TN, (N + TM - 1) / TM);
    gemm_mfma_dual_kernel<<<gg, 256, 0, stream>>>(
        Ah[L], Al[L], WlT_h[L], WlT_l[L], WrT_h[L], WrT_l[L], fs, fd, N, K, M);
    if (L == 0) {
      node_attn_kernel<128><<<(N + 3) / 4, 256, 0, stream>>>(
          fs, fd, rowptr, csrc, attn[L], bias[L], nullptr, h1hi, h1lo, N);
    } else if (L == 1) {
      node_attn_kernel<128><<<(N + 3) / 4, 256, 0, stream>>>(
          fs, fd, rowptr, csrc, attn[L], bias[L], nullptr, h2hi, h2lo, N);
    } else {
      node_attn_kernel<64><<<(N + 3) / 4, 256, 0, stream>>>(
          fs, fd, rowptr, csrc, attn[L], bias[L], hfin, nullptr, nullptr, N);
    }
  }

  hipMemsetAsync(d_out, 0, 64 * sizeof(float), stream);
  final_mean_kernel<<<256, 64, 0, stream>>>(hfin, (float*)d_out, N);
}

// Round 6
// 492.601 us; speedup vs baseline: 6.2976x; 1.0348x over previous
//
#include <hip/hip_runtime.h>
#include <hip/hip_bf16.h>
#include <stdint.h>

// GATv2 3-layer network. Round 5:
//  - XCD-affinity grid swizzle in GEMM: all column-blocks of one A row-strip
//    map to the same XCD (id%8) so the A-strip stays in that XCD's L2.
//  - node_attn edge loop unrolled x4 (4 independent gathers in flight).
//  - Otherwise: global_load_lds staging, 3-term split-bf16 MFMA, fp16 fs/fd,
//    CSR attn, fused bf16-split epilogue.

#define GAT_SLOPE 0.2f
#define ACT_SLOPE 0.01f

typedef short short8 __attribute__((ext_vector_type(8)));
typedef float floatx4 __attribute__((ext_vector_type(4)));

// ---------------- fp32 -> (hi, lo) bf16 split helpers ----------------
__device__ __forceinline__ unsigned short bf16_rn(float x) {
  unsigned u = __float_as_uint(x);
  unsigned r = (u + 0x7FFFu + ((u >> 16) & 1u)) >> 16;
  return (unsigned short)r;
}
__device__ __forceinline__ float bf16_to_f(unsigned short h) {
  return __uint_as_float(((unsigned)h) << 16);
}

__global__ __launch_bounds__(256) void split_kernel(
    const float* __restrict__ in, unsigned short* __restrict__ hi,
    unsigned short* __restrict__ lo, int n) {
  for (int i = blockIdx.x * 256 + threadIdx.x; i < n; i += gridDim.x * 256) {
    float a = in[i];
    unsigned short h = bf16_rn(a);
    hi[i] = h;
    lo[i] = bf16_rn(a - bf16_to_f(h));
  }
}

// ---------------- merged weight transpose+split (all 6 matrices) ----------------
struct TransDesc {
  const float* src;
  unsigned short* hi;
  unsigned short* lo;
  int K, M, off;
};
struct TransArgs {
  TransDesc d[6];
  int total;
};

__global__ __launch_bounds__(256) void transpose_all_kernel(TransArgs ta) {
  int i = blockIdx.x * 256 + threadIdx.x;
  if (i >= ta.total) return;
  int q = 0;
#pragma unroll
  for (int j = 1; j < 6; ++j)
    if (i >= ta.d[j].off) q = j;
  int local = i - ta.d[q].off;
  int K = ta.d[q].K, M = ta.d[q].M;
  int k = local / M, m = local % M;
  float a = ta.d[q].src[local];
  unsigned short h = bf16_rn(a);
  ta.d[q].hi[(size_t)m * K + k] = h;
  ta.d[q].lo[(size_t)m * K + k] = bf16_rn(a - bf16_to_f(h));
}

// ---------------- async global -> LDS (16B per lane) ----------------
__device__ __forceinline__ void gload_lds16(const unsigned short* g,
                                            unsigned short* l) {
  __builtin_amdgcn_global_load_lds(
      (__attribute__((address_space(1))) unsigned int*)g,
      (__attribute__((address_space(3))) unsigned int*)l, 16, 0, 0);
}

// ---------------- split-bf16 MFMA GEMM, dual-B, fp16 output ----------------
// C0[N,M]=A@B0, C1[N,M]=A@B1. A hi/lo bf16 [N,K]; B hi/lo bf16 [M,K].
// 128x128 tile, 256 threads (4 waves), TK=32, 16x16x32 MFMA, 3-term split.
// Grid: 1D, S8*nbx blocks (S8 = strips padded to x8, nbx = 2M/TN).
// XCD swizzle: xcd=id&7, s=id>>3, col=s&(nbx-1), chunk=s>>nbxLog2,
// strip=chunk*8+xcd  -> one strip's column blocks share an XCD (A reuse in L2).
#define TM 128
#define TN 128
#define TK 32

__global__ __launch_bounds__(256) void gemm_mfma_dual_kernel(
    const unsigned short* __restrict__ Ahi, const unsigned short* __restrict__ Alo,
    const unsigned short* __restrict__ B0hi, const unsigned short* __restrict__ B0lo,
    const unsigned short* __restrict__ B1hi, const unsigned short* __restrict__ B1lo,
    _Float16* __restrict__ C0, _Float16* __restrict__ C1, int Nrow, int K,
    int M, int nStrips, int nbxLog2) {
  const int id = blockIdx.x;
  const int xcd = id & 7;
  const int s = id >> 3;
  const int nbx = 1 << nbxLog2;
  const int col = s & (nbx - 1);
  const int chunk = s >> nbxLog2;
  const int strip = chunk * 8 + xcd;
  if (strip >= nStrips) return;

  const int nb = nbx >> 1;  // column blocks per B matrix
  const bool second = col >= nb;
  const unsigned short* Bhi = second ? B1hi : B0hi;
  const unsigned short* Blo = second ? B1lo : B0lo;
  _Float16* C = second ? C1 : C0;
  const int bn = (second ? col - nb : col) * TN;
  const int bm = strip * TM;

  __shared__ __align__(16) unsigned short AsH[TM * TK];
  __shared__ __align__(16) unsigned short AsL[TM * TK];
  __shared__ __align__(16) unsigned short BsH[TN * TK];
  __shared__ __align__(16) unsigned short BsL[TN * TK];

  const int tid = threadIdx.x;
  const int w = tid >> 6;
  const int lane = tid & 63;
  const int wr = w >> 1;
  const int wc = w & 1;
  const int quad = lane >> 4;
  const int lr = lane & 15;

  const int lrow = lane >> 2;
  const int loff = (lane & 3) * 8;

  floatx4 acc[4][4];
#pragma unroll
  for (int i = 0; i < 4; ++i)
#pragma unroll
    for (int j = 0; j < 4; ++j) acc[i][j] = (floatx4){0.f, 0.f, 0.f, 0.f};

  const int KT = K / TK;
  for (int kt = 0; kt < KT; ++kt) {
    const int k0 = kt * TK;
#pragma unroll
    for (int half = 0; half < 2; ++half) {
      const int r0 = w * 32 + half * 16;
      int ga = bm + r0 + lrow;
      if (ga >= Nrow) ga = Nrow - 1;
      const size_t aoff = (size_t)ga * K + k0 + loff;
      gload_lds16(Ahi + aoff, AsH + r0 * TK);
      gload_lds16(Alo + aoff, AsL + r0 * TK);
      const size_t boff = (size_t)(bn + r0 + lrow) * K + k0 + loff;
      gload_lds16(Bhi + boff, BsH + r0 * TK);
      gload_lds16(Blo + boff, BsL + r0 * TK);
    }
    __syncthreads();

    short8 ah[4], al[4], bh[4], bl[4];
#pragma unroll
    for (int i = 0; i < 4; ++i) {
      int row = wr * 64 + i * 16 + lr;
      int l = row * TK + quad * 8;
      ah[i] = *(const short8*)(AsH + l);
      al[i] = *(const short8*)(AsL + l);
    }
#pragma unroll
    for (int j = 0; j < 4; ++j) {
      int colr = wc * 64 + j * 16 + lr;
      int l = colr * TK + quad * 8;
      bh[j] = *(const short8*)(BsH + l);
      bl[j] = *(const short8*)(BsL + l);
    }
#pragma unroll
    for (int i = 0; i < 4; ++i)
#pragma unroll
      for (int j = 0; j < 4; ++j) {
        acc[i][j] = __builtin_amdgcn_mfma_f32_16x16x32_bf16(ah[i], bh[j],
                                                            acc[i][j], 0, 0, 0);
        acc[i][j] = __builtin_amdgcn_mfma_f32_16x16x32_bf16(al[i], bh[j],
                                                            acc[i][j], 0, 0, 0);
        acc[i][j] = __builtin_amdgcn_mfma_f32_16x16x32_bf16(ah[i], bl[j],
                                                            acc[i][j], 0, 0, 0);
      }
    __syncthreads();
  }

#pragma unroll
  for (int i = 0; i < 4; ++i) {
#pragma unroll
    for (int r = 0; r < 4; ++r) {
      int row = bm + wr * 64 + i * 16 + quad * 4 + r;
      if (row >= Nrow) continue;
#pragma unroll
      for (int j = 0; j < 4; ++j) {
        int colc = bn + wc * 64 + j * 16 + lr;
        C[(size_t)row * M + colc] = (_Float16)acc[i][j][r];
      }
    }
  }
}

// ---------------- CSR build (stores src directly) ----------------
__global__ __launch_bounds__(256) void hist_kernel(const int* __restrict__ dst,
                                                   int* __restrict__ counts,
                                                   int E) {
  int e = blockIdx.x * 256 + threadIdx.x;
  if (e < E) atomicAdd(&counts[dst[e]], 1);
}

__global__ __launch_bounds__(256) void scan_kernel(
    const int* __restrict__ counts, int* __restrict__ rowptr,
    int* __restrict__ cursor, int N) {
  __shared__ int sums[256];
  const int t = threadIdx.x;
  const int C = (N + 255) / 256;
  const int lo = t * C;
  const int hi = min(lo + C, N);
  int s = 0;
  for (int i = lo; i < hi; ++i) s += counts[i];
  sums[t] = s;
  __syncthreads();
  for (int off = 1; off < 256; off <<= 1) {
    int v = (t >= off) ? sums[t - off] : 0;
    __syncthreads();
    sums[t] += v;
    __syncthreads();
  }
  int run = (t == 0) ? 0 : sums[t - 1];
  for (int i = lo; i < hi; ++i) {
    rowptr[i] = run;
    cursor[i] = run;
    run += counts[i];
  }
  if (t == 255) rowptr[N] = run;
}

__global__ __launch_bounds__(256) void scatter_kernel(
    const int* __restrict__ src, const int* __restrict__ dst,
    int* __restrict__ cursor, int* __restrict__ csrc, int E) {
  int e = blockIdx.x * 256 + threadIdx.x;
  if (e < E) {
    int p = atomicAdd(&cursor[dst[e]], 1);
    csrc[p] = src[e];
  }
}

// ---------------- fused per-node GATv2 attention (fp16, unroll x4) ----------------
template <int D>
__global__ __launch_bounds__(256) void node_attn_kernel(
    const _Float16* __restrict__ fs, const _Float16* __restrict__ fd,
    const int* __restrict__ rowptr, const int* __restrict__ csrc,
    const float* __restrict__ attn, const float* __restrict__ bias,
    float* __restrict__ hout, unsigned short* __restrict__ ohi,
    unsigned short* __restrict__ olo, int N) {
  constexpr int HD = 4 * D;
  constexpr int R = HD / 64;
  typedef _Float16 halfR __attribute__((ext_vector_type(R)));
  const int v = blockIdx.x * 4 + (threadIdx.x >> 6);
  if (v >= N) return;
  const int lane = threadIdx.x & 63;

  float fdr[R], ar[R];
  {
    halfR t = *(const halfR*)(fd + (size_t)v * HD + lane * R);
#pragma unroll
    for (int i = 0; i < R; ++i) fdr[i] = (float)t[i];
  }
#pragma unroll
  for (int i = 0; i < R; ++i) ar[i] = attn[lane * R + i];

  float m = -INFINITY, l = 0.f;
  float O[R];
#pragma unroll
  for (int i = 0; i < R; ++i) O[i] = 0.f;

  const int e0 = rowptr[v];
  const int e1 = rowptr[v + 1];
  int k = e0;
  for (; k + 3 < e1; k += 4) {
    const int s0 = csrc[k];
    const int s1 = csrc[k + 1];
    const int s2 = csrc[k + 2];
    const int s3 = csrc[k + 3];
    halfR t0 = *(const halfR*)(fs + (size_t)s0 * HD + lane * R);
    halfR t1 = *(const halfR*)(fs + (size_t)s1 * HD + lane * R);
    halfR t2 = *(const halfR*)(fs + (size_t)s2 * HD + lane * R);
    halfR t3 = *(const halfR*)(fs + (size_t)s3 * HD + lane * R);
    float f0[R], f1[R], f2[R], f3[R];
#pragma unroll
    for (int i = 0; i < R; ++i) {
      f0[i] = (float)t0[i];
      f1[i] = (float)t1[i];
      f2[i] = (float)t2[i];
      f3[i] = (float)t3[i];
    }
    float p0 = 0.f, p1 = 0.f, p2 = 0.f, p3 = 0.f;
#pragma unroll
    for (int i = 0; i < R; ++i) {
      float x0 = f0[i] + fdr[i];
      float x1 = f1[i] + fdr[i];
      float x2 = f2[i] + fdr[i];
      float x3 = f3[i] + fdr[i];
      x0 = x0 > 0.f ? x0 : x0 * GAT_SLOPE;
      x1 = x1 > 0.f ? x1 : x1 * GAT_SLOPE;
      x2 = x2 > 0.f ? x2 : x2 * GAT_SLOPE;
      x3 = x3 > 0.f ? x3 : x3 * GAT_SLOPE;
      p0 += ar[i] * x0;
      p1 += ar[i] * x1;
      p2 += ar[i] * x2;
      p3 += ar[i] * x3;
    }
#pragma unroll
    for (int off = 1; off <= 8; off <<= 1) {
      p0 += __shfl_xor(p0, off, 64);
      p1 += __shfl_xor(p1, off, 64);
      p2 += __shfl_xor(p2, off, 64);
      p3 += __shfl_xor(p3, off, 64);
    }
    const float mq = fmaxf(fmaxf(p0, p1), fmaxf(p2, p3));
    const float w0 = __expf(p0 - mq);
    const float w1 = __expf(p1 - mq);
    const float w2 = __expf(p2 - mq);
    const float w3 = __expf(p3 - mq);
    const float mnew = fmaxf(m, mq);
    const float sc = __expf(m - mnew);
    const float sq = __expf(mq - mnew);
    l = l * sc + (w0 + w1 + w2 + w3) * sq;
#pragma unroll
    for (int i = 0; i < R; ++i)
      O[i] = O[i] * sc +
             sq * (w0 * f0[i] + w1 * f1[i] + w2 * f2[i] + w3 * f3[i]);
    m = mnew;
  }
  for (; k < e1; ++k) {
    const int s0 = csrc[k];
    halfR t0 = *(const halfR*)(fs + (size_t)s0 * HD + lane * R);
    float f0[R];
#pragma unroll
    for (int i = 0; i < R; ++i) f0[i] = (float)t0[i];
    float p0 = 0.f;
#pragma unroll
    for (int i = 0; i < R; ++i) {
      float x = f0[i] + fdr[i];
      x = x > 0.f ? x : x * GAT_SLOPE;
      p0 += ar[i] * x;
    }
#pragma unroll
    for (int off = 1; off <= 8; off <<= 1) p0 += __shfl_xor(p0, off, 64);
    const float mnew = fmaxf(m, p0);
    const float sc = __expf(m - mnew);
    const float p = __expf(p0 - mnew);
    l = l * sc + p;
#pragma unroll
    for (int i = 0; i < R; ++i) O[i] = O[i] * sc + p * f0[i];
    m = mnew;
  }

  const float inv = (l > 0.f) ? 1.f / l : 0.f;
#pragma unroll
  for (int i = 0; i < R; ++i) O[i] = O[i] * inv + bias[lane * R + i];
#pragma unroll
  for (int i = 0; i < R; ++i) {
    O[i] += __shfl_xor(O[i], 16, 64);
    O[i] += __shfl_xor(O[i], 32, 64);
    float x = O[i] * 0.25f;
    O[i] = x > 0.f ? x : x * ACT_SLOPE;
  }
  if (lane < 16) {
    const size_t base = (size_t)v * D + lane * R;
    if (hout) {
#pragma unroll
      for (int i = 0; i < R; ++i) hout[base + i] = O[i];
    }
    if (ohi) {
#pragma unroll
      for (int i = 0; i < R; ++i) {
        unsigned short h = bf16_rn(O[i]);
        ohi[base + i] = h;
        olo[base + i] = bf16_rn(O[i] - bf16_to_f(h));
      }
    }
  }
}

// ------------- out[d] = mean_n h[n,d] -------------
__global__ __launch_bounds__(64) void final_mean_kernel(
    const float* __restrict__ h, float* __restrict__ out, int N) {
  const int d = threadIdx.x;
  float acc = 0.f;
  for (int n = blockIdx.x; n < N; n += gridDim.x) acc += h[(size_t)n * 64 + d];
  atomicAdd(&out[d], acc / (float)N);
}

// ------------------------------------------------------------------
extern "C" void kernel_launch(void* const* d_in, const int* in_sizes, int n_in,
                              void* d_out, int out_size, void* d_ws,
                              size_t ws_size, hipStream_t stream) {
  const float* n_feat = (const float*)d_in[0];
  const int* src = (const int*)d_in[1];
  const int* dst = (const int*)d_in[2];
  const float* Wl[3] = {(const float*)d_in[3], (const float*)d_in[7],
                        (const float*)d_in[11]};
  const float* Wr[3] = {(const float*)d_in[4], (const float*)d_in[8],
                        (const float*)d_in[12]};
  const float* attn[3] = {(const float*)d_in[5], (const float*)d_in[9],
                          (const float*)d_in[13]};
  const float* bias[3] = {(const float*)d_in[6], (const float*)d_in[10],
                          (const float*)d_in[14]};

  const int N = in_sizes[0] / 512;  // 20000
  const int E = in_sizes[1];        // 320000
  const int Kdim[3] = {512, 128, 128};
  const int Mdim[3] = {512, 512, 256};

  char* ws = (char*)d_ws;
  size_t o = 0;
  auto alloc = [&](size_t bytes) {
    void* p = ws + o;
    o += (bytes + 15) & ~(size_t)15;
    return p;
  };
  _Float16* fs = (_Float16*)alloc((size_t)N * 512 * 2);
  _Float16* fd = (_Float16*)alloc((size_t)N * 512 * 2);
  unsigned short* A0hi = (unsigned short*)alloc((size_t)N * 512 * 2);
  unsigned short* A0lo = (unsigned short*)alloc((size_t)N * 512 * 2);
  unsigned short* h1hi = (unsigned short*)alloc((size_t)N * 128 * 2);
  unsigned short* h1lo = (unsigned short*)alloc((size_t)N * 128 * 2);
  unsigned short* h2hi = (unsigned short*)alloc((size_t)N * 128 * 2);
  unsigned short* h2lo = (unsigned short*)alloc((size_t)N * 128 * 2);
  float* hfin = (float*)alloc((size_t)N * 64 * 4);
  unsigned short *WlT_h[3], *WlT_l[3], *WrT_h[3], *WrT_l[3];
  for (int L = 0; L < 3; ++L) {
    size_t sz = (size_t)Kdim[L] * Mdim[L] * 2;
    WlT_h[L] = (unsigned short*)alloc(sz);
    WlT_l[L] = (unsigned short*)alloc(sz);
    WrT_h[L] = (unsigned short*)alloc(sz);
    WrT_l[L] = (unsigned short*)alloc(sz);
  }
  int* counts = (int*)alloc((size_t)N * 4);
  int* rowptr = (int*)alloc((size_t)(N + 1) * 4);
  int* cursor = (int*)alloc((size_t)N * 4);
  int* csrc = (int*)alloc((size_t)E * 4);

  // ---- merged weight transpose+split (1 launch) ----
  {
    TransArgs ta;
    int off = 0;
    for (int L = 0; L < 3; ++L) {
      ta.d[2 * L] = {Wl[L], WlT_h[L], WlT_l[L], Kdim[L], Mdim[L], off};
      off += Kdim[L] * Mdim[L];
      ta.d[2 * L + 1] = {Wr[L], WrT_h[L], WrT_l[L], Kdim[L], Mdim[L], off};
      off += Kdim[L] * Mdim[L];
    }
    ta.total = off;
    transpose_all_kernel<<<(ta.total + 255) / 256, 256, 0, stream>>>(ta);
  }

  // ---- split layer-0 input ----
  split_kernel<<<1024, 256, 0, stream>>>(n_feat, A0hi, A0lo, N * 512);

  // ---- CSR by dst ----
  hipMemsetAsync(counts, 0, (size_t)N * sizeof(int), stream);
  hist_kernel<<<(E + 255) / 256, 256, 0, stream>>>(dst, counts, E);
  scan_kernel<<<1, 256, 0, stream>>>(counts, rowptr, cursor, N);
  scatter_kernel<<<(E + 255) / 256, 256, 0, stream>>>(src, dst, cursor, csrc,
                                                      E);

  const unsigned short* Ah[3] = {A0hi, h1hi, h2hi};
  const unsigned short* Al[3] = {A0lo, h1lo, h2lo};

  const int nStrips = (N + TM - 1) / TM;           // 157
  const int S8 = ((nStrips + 7) / 8) * 8;          // 160

  for (int L = 0; L < 3; ++L) {
    const int K = Kdim[L], M = Mdim[L];
    const int nbx = 2 * M / TN;                    // 8 or 4
    const int nbxLog2 = (nbx == 8) ? 3 : 2;
    gemm_mfma_dual_kernel<<<S8 * nbx, 256, 0, stream>>>(
        Ah[L], Al[L], WlT_h[L], WlT_l[L], WrT_h[L], WrT_l[L], fs, fd, N, K, M,
        nStrips, nbxLog2);
    if (L == 0) {
      node_attn_kernel<128><<<(N + 3) / 4, 256, 0, stream>>>(
          fs, fd, rowptr, csrc, attn[L], bias[L], nullptr, h1hi, h1lo, N);
    } else if (L == 1) {
      node_attn_kernel<128><<<(N + 3) / 4, 256, 0, stream>>>(
          fs, fd, rowptr, csrc, attn[L], bias[L], nullptr, h2hi, h2lo, N);
    } else {
      node_attn_kernel<64><<<(N + 3) / 4, 256, 0, stream>>>(
          fs, fd, rowptr, csrc, attn[L], bias[L], hfin, nullptr, nullptr, N);
    }
  }

  hipMemsetAsync(d_out, 0, 64 * sizeof(float), stream);
  final_mean_kernel<<<256, 64, 0, stream>>>(hfin, (float*)d_out, N);
}

// Round 7
// 445.677 us; speedup vs baseline: 6.9606x; 1.1053x over previous
//
#include <hip/hip_runtime.h>
#include <hip/hip_bf16.h>
#include <stdint.h>

// GATv2 3-layer network. Round 6: pure fp16 MFMA GEMM (1 term instead of
// 3-term bf16 split; fp32 accumulate). Whole activation chain fp16.
// Keeps: XCD-affinity swizzle, global_load_lds staging, CSR attn unroll x4.

#define GAT_SLOPE 0.2f
#define ACT_SLOPE 0.01f

typedef _Float16 half8 __attribute__((ext_vector_type(8)));
typedef float floatx4 __attribute__((ext_vector_type(4)));

// ---------------- fp32 -> fp16 convert (layer-0 input) ----------------
__global__ __launch_bounds__(256) void cvt_half_kernel(
    const float* __restrict__ in, _Float16* __restrict__ out, int n) {
  for (int i = blockIdx.x * 256 + threadIdx.x; i < n; i += gridDim.x * 256)
    out[i] = (_Float16)in[i];
}

// ---------------- merged weight transpose (all 6 matrices, fp32->fp16) ------
struct TransDesc {
  const float* src;
  _Float16* dst;
  int K, M, off;
};
struct TransArgs {
  TransDesc d[6];
  int total;
};

__global__ __launch_bounds__(256) void transpose_all_kernel(TransArgs ta) {
  int i = blockIdx.x * 256 + threadIdx.x;
  if (i >= ta.total) return;
  int q = 0;
#pragma unroll
  for (int j = 1; j < 6; ++j)
    if (i >= ta.d[j].off) q = j;
  int local = i - ta.d[q].off;
  int K = ta.d[q].K, M = ta.d[q].M;
  int k = local / M, m = local % M;
  ta.d[q].dst[(size_t)m * K + k] = (_Float16)ta.d[q].src[local];
}

// ---------------- async global -> LDS (16B per lane) ----------------
__device__ __forceinline__ void gload_lds16(const _Float16* g, _Float16* l) {
  __builtin_amdgcn_global_load_lds(
      (__attribute__((address_space(1))) unsigned int*)g,
      (__attribute__((address_space(3))) unsigned int*)l, 16, 0, 0);
}

// ---------------- fp16 MFMA GEMM, dual-B, fp16 output ----------------
// C0[N,M]=A@B0, C1[N,M]=A@B1. A fp16 [N,K]; B fp16 [M,K] (pre-transposed).
// 128x128 tile, 256 threads (4 waves), TK=32, 16x16x32 f16 MFMA.
// XCD swizzle: all column-blocks of one A row-strip share an XCD.
#define TM 128
#define TN 128
#define TK 32

__global__ __launch_bounds__(256) void gemm_mfma_dual_kernel(
    const _Float16* __restrict__ A, const _Float16* __restrict__ B0,
    const _Float16* __restrict__ B1, _Float16* __restrict__ C0,
    _Float16* __restrict__ C1, int Nrow, int K, int M, int nStrips,
    int nbxLog2) {
  const int id = blockIdx.x;
  const int xcd = id & 7;
  const int s = id >> 3;
  const int nbx = 1 << nbxLog2;
  const int col = s & (nbx - 1);
  const int chunk = s >> nbxLog2;
  const int strip = chunk * 8 + xcd;
  if (strip >= nStrips) return;

  const int nb = nbx >> 1;
  const bool second = col >= nb;
  const _Float16* B = second ? B1 : B0;
  _Float16* C = second ? C1 : C0;
  const int bn = (second ? col - nb : col) * TN;
  const int bm = strip * TM;

  __shared__ __align__(16) _Float16 As[TM * TK];
  __shared__ __align__(16) _Float16 Bs[TN * TK];

  const int tid = threadIdx.x;
  const int w = tid >> 6;
  const int lane = tid & 63;
  const int wr = w >> 1;
  const int wc = w & 1;
  const int quad = lane >> 4;
  const int lr = lane & 15;

  const int lrow = lane >> 2;       // 16 rows per DMA instruction
  const int loff = (lane & 3) * 8;  // 4 lanes x 8 fp16 = 64B row

  floatx4 acc[4][4];
#pragma unroll
  for (int i = 0; i < 4; ++i)
#pragma unroll
    for (int j = 0; j < 4; ++j) acc[i][j] = (floatx4){0.f, 0.f, 0.f, 0.f};

  const int KT = K / TK;
  for (int kt = 0; kt < KT; ++kt) {
    const int k0 = kt * TK;
#pragma unroll
    for (int half = 0; half < 2; ++half) {
      const int r0 = w * 32 + half * 16;
      int ga = bm + r0 + lrow;
      if (ga >= Nrow) ga = Nrow - 1;  // clamp; clamped outputs discarded
      gload_lds16(A + (size_t)ga * K + k0 + loff, As + r0 * TK);
      gload_lds16(B + (size_t)(bn + r0 + lrow) * K + k0 + loff,
                  Bs + r0 * TK);
    }
    __syncthreads();

    half8 ar[4], br[4];
#pragma unroll
    for (int i = 0; i < 4; ++i) {
      int row = wr * 64 + i * 16 + lr;
      ar[i] = *(const half8*)(As + row * TK + quad * 8);
    }
#pragma unroll
    for (int j = 0; j < 4; ++j) {
      int colr = wc * 64 + j * 16 + lr;
      br[j] = *(const half8*)(Bs + colr * TK + quad * 8);
    }
#pragma unroll
    for (int i = 0; i < 4; ++i)
#pragma unroll
      for (int j = 0; j < 4; ++j)
        acc[i][j] = __builtin_amdgcn_mfma_f32_16x16x32_f16(ar[i], br[j],
                                                           acc[i][j], 0, 0, 0);
    __syncthreads();
  }

  // epilogue: C/D layout col=lane&15, row=quad*4+reg
#pragma unroll
  for (int i = 0; i < 4; ++i) {
#pragma unroll
    for (int r = 0; r < 4; ++r) {
      int row = bm + wr * 64 + i * 16 + quad * 4 + r;
      if (row >= Nrow) continue;
#pragma unroll
      for (int j = 0; j < 4; ++j) {
        int colc = bn + wc * 64 + j * 16 + lr;
        C[(size_t)row * M + colc] = (_Float16)acc[i][j][r];
      }
    }
  }
}

// ---------------- CSR build (stores src directly) ----------------
__global__ __launch_bounds__(256) void hist_kernel(const int* __restrict__ dst,
                                                   int* __restrict__ counts,
                                                   int E) {
  int e = blockIdx.x * 256 + threadIdx.x;
  if (e < E) atomicAdd(&counts[dst[e]], 1);
}

__global__ __launch_bounds__(256) void scan_kernel(
    const int* __restrict__ counts, int* __restrict__ rowptr,
    int* __restrict__ cursor, int N) {
  __shared__ int sums[256];
  const int t = threadIdx.x;
  const int C = (N + 255) / 256;
  const int lo = t * C;
  const int hi = min(lo + C, N);
  int s = 0;
  for (int i = lo; i < hi; ++i) s += counts[i];
  sums[t] = s;
  __syncthreads();
  for (int off = 1; off < 256; off <<= 1) {
    int v = (t >= off) ? sums[t - off] : 0;
    __syncthreads();
    sums[t] += v;
    __syncthreads();
  }
  int run = (t == 0) ? 0 : sums[t - 1];
  for (int i = lo; i < hi; ++i) {
    rowptr[i] = run;
    cursor[i] = run;
    run += counts[i];
  }
  if (t == 255) rowptr[N] = run;
}

__global__ __launch_bounds__(256) void scatter_kernel(
    const int* __restrict__ src, const int* __restrict__ dst,
    int* __restrict__ cursor, int* __restrict__ csrc, int E) {
  int e = blockIdx.x * 256 + threadIdx.x;
  if (e < E) {
    int p = atomicAdd(&cursor[dst[e]], 1);
    csrc[p] = src[e];
  }
}

// ---------------- fused per-node GATv2 attention (fp16, unroll x4) ----------
// One wave per dst node, 4 nodes/block. Epilogue: fp16 next-layer A (oh)
// and/or fp32 h (hout).
template <int D>
__global__ __launch_bounds__(256) void node_attn_kernel(
    const _Float16* __restrict__ fs, const _Float16* __restrict__ fd,
    const int* __restrict__ rowptr, const int* __restrict__ csrc,
    const float* __restrict__ attn, const float* __restrict__ bias,
    float* __restrict__ hout, _Float16* __restrict__ oh, int N) {
  constexpr int HD = 4 * D;
  constexpr int R = HD / 64;
  typedef _Float16 halfR __attribute__((ext_vector_type(R)));
  const int v = blockIdx.x * 4 + (threadIdx.x >> 6);
  if (v >= N) return;
  const int lane = threadIdx.x & 63;

  float fdr[R], ar[R];
  {
    halfR t = *(const halfR*)(fd + (size_t)v * HD + lane * R);
#pragma unroll
    for (int i = 0; i < R; ++i) fdr[i] = (float)t[i];
  }
#pragma unroll
  for (int i = 0; i < R; ++i) ar[i] = attn[lane * R + i];

  float m = -INFINITY, l = 0.f;
  float O[R];
#pragma unroll
  for (int i = 0; i < R; ++i) O[i] = 0.f;

  const int e0 = rowptr[v];
  const int e1 = rowptr[v + 1];
  int k = e0;
  for (; k + 3 < e1; k += 4) {
    const int s0 = csrc[k];
    const int s1 = csrc[k + 1];
    const int s2 = csrc[k + 2];
    const int s3 = csrc[k + 3];
    halfR t0 = *(const halfR*)(fs + (size_t)s0 * HD + lane * R);
    halfR t1 = *(const halfR*)(fs + (size_t)s1 * HD + lane * R);
    halfR t2 = *(const halfR*)(fs + (size_t)s2 * HD + lane * R);
    halfR t3 = *(const halfR*)(fs + (size_t)s3 * HD + lane * R);
    float f0[R], f1[R], f2[R], f3[R];
#pragma unroll
    for (int i = 0; i < R; ++i) {
      f0[i] = (float)t0[i];
      f1[i] = (float)t1[i];
      f2[i] = (float)t2[i];
      f3[i] = (float)t3[i];
    }
    float p0 = 0.f, p1 = 0.f, p2 = 0.f, p3 = 0.f;
#pragma unroll
    for (int i = 0; i < R; ++i) {
      float x0 = f0[i] + fdr[i];
      float x1 = f1[i] + fdr[i];
      float x2 = f2[i] + fdr[i];
      float x3 = f3[i] + fdr[i];
      x0 = x0 > 0.f ? x0 : x0 * GAT_SLOPE;
      x1 = x1 > 0.f ? x1 : x1 * GAT_SLOPE;
      x2 = x2 > 0.f ? x2 : x2 * GAT_SLOPE;
      x3 = x3 > 0.f ? x3 : x3 * GAT_SLOPE;
      p0 += ar[i] * x0;
      p1 += ar[i] * x1;
      p2 += ar[i] * x2;
      p3 += ar[i] * x3;
    }
#pragma unroll
    for (int off = 1; off <= 8; off <<= 1) {
      p0 += __shfl_xor(p0, off, 64);
      p1 += __shfl_xor(p1, off, 64);
      p2 += __shfl_xor(p2, off, 64);
      p3 += __shfl_xor(p3, off, 64);
    }
    const float mq = fmaxf(fmaxf(p0, p1), fmaxf(p2, p3));
    const float w0 = __expf(p0 - mq);
    const float w1 = __expf(p1 - mq);
    const float w2 = __expf(p2 - mq);
    const float w3 = __expf(p3 - mq);
    const float mnew = fmaxf(m, mq);
    const float sc = __expf(m - mnew);
    const float sq = __expf(mq - mnew);
    l = l * sc + (w0 + w1 + w2 + w3) * sq;
#pragma unroll
    for (int i = 0; i < R; ++i)
      O[i] = O[i] * sc +
             sq * (w0 * f0[i] + w1 * f1[i] + w2 * f2[i] + w3 * f3[i]);
    m = mnew;
  }
  for (; k < e1; ++k) {
    const int s0 = csrc[k];
    halfR t0 = *(const halfR*)(fs + (size_t)s0 * HD + lane * R);
    float f0[R];
#pragma unroll
    for (int i = 0; i < R; ++i) f0[i] = (float)t0[i];
    float p0 = 0.f;
#pragma unroll
    for (int i = 0; i < R; ++i) {
      float x = f0[i] + fdr[i];
      x = x > 0.f ? x : x * GAT_SLOPE;
      p0 += ar[i] * x;
    }
#pragma unroll
    for (int off = 1; off <= 8; off <<= 1) p0 += __shfl_xor(p0, off, 64);
    const float mnew = fmaxf(m, p0);
    const float sc = __expf(m - mnew);
    const float p = __expf(p0 - mnew);
    l = l * sc + p;
#pragma unroll
    for (int i = 0; i < R; ++i) O[i] = O[i] * sc + p * f0[i];
    m = mnew;
  }

  const float inv = (l > 0.f) ? 1.f / l : 0.f;
#pragma unroll
  for (int i = 0; i < R; ++i) O[i] = O[i] * inv + bias[lane * R + i];
#pragma unroll
  for (int i = 0; i < R; ++i) {
    O[i] += __shfl_xor(O[i], 16, 64);
    O[i] += __shfl_xor(O[i], 32, 64);
    float x = O[i] * 0.25f;
    O[i] = x > 0.f ? x : x * ACT_SLOPE;
  }
  if (lane < 16) {
    const size_t base = (size_t)v * D + lane * R;
    if (hout) {
#pragma unroll
      for (int i = 0; i < R; ++i) hout[base + i] = O[i];
    }
    if (oh) {
#pragma unroll
      for (int i = 0; i < R; ++i) oh[base + i] = (_Float16)O[i];
    }
  }
}

// ------------- out[d] = mean_n h[n,d] -------------
__global__ __launch_bounds__(64) void final_mean_kernel(
    const float* __restrict__ h, float* __restrict__ out, int N) {
  const int d = threadIdx.x;
  float acc = 0.f;
  for (int n = blockIdx.x; n < N; n += gridDim.x) acc += h[(size_t)n * 64 + d];
  atomicAdd(&out[d], acc / (float)N);
}

// ------------------------------------------------------------------
extern "C" void kernel_launch(void* const* d_in, const int* in_sizes, int n_in,
                              void* d_out, int out_size, void* d_ws,
                              size_t ws_size, hipStream_t stream) {
  const float* n_feat = (const float*)d_in[0];
  const int* src = (const int*)d_in[1];
  const int* dst = (const int*)d_in[2];
  const float* Wl[3] = {(const float*)d_in[3], (const float*)d_in[7],
                        (const float*)d_in[11]};
  const float* Wr[3] = {(const float*)d_in[4], (const float*)d_in[8],
                        (const float*)d_in[12]};
  const float* attn[3] = {(const float*)d_in[5], (const float*)d_in[9],
                          (const float*)d_in[13]};
  const float* bias[3] = {(const float*)d_in[6], (const float*)d_in[10],
                          (const float*)d_in[14]};

  const int N = in_sizes[0] / 512;  // 20000
  const int E = in_sizes[1];        // 320000
  const int Kdim[3] = {512, 128, 128};
  const int Mdim[3] = {512, 512, 256};

  char* ws = (char*)d_ws;
  size_t o = 0;
  auto alloc = [&](size_t bytes) {
    void* p = ws + o;
    o += (bytes + 15) & ~(size_t)15;
    return p;
  };
  _Float16* fs = (_Float16*)alloc((size_t)N * 512 * 2);
  _Float16* fd = (_Float16*)alloc((size_t)N * 512 * 2);
  _Float16* A0 = (_Float16*)alloc((size_t)N * 512 * 2);
  _Float16* h1 = (_Float16*)alloc((size_t)N * 128 * 2);
  _Float16* h2 = (_Float16*)alloc((size_t)N * 128 * 2);
  float* hfin = (float*)alloc((size_t)N * 64 * 4);
  _Float16 *WlT[3], *WrT[3];
  for (int L = 0; L < 3; ++L) {
    size_t sz = (size_t)Kdim[L] * Mdim[L] * 2;
    WlT[L] = (_Float16*)alloc(sz);
    WrT[L] = (_Float16*)alloc(sz);
  }
  int* counts = (int*)alloc((size_t)N * 4);
  int* rowptr = (int*)alloc((size_t)(N + 1) * 4);
  int* cursor = (int*)alloc((size_t)N * 4);
  int* csrc = (int*)alloc((size_t)E * 4);

  // ---- merged weight transpose (1 launch, fp32 -> fp16 [M][K]) ----
  {
    TransArgs ta;
    int off = 0;
    for (int L = 0; L < 3; ++L) {
      ta.d[2 * L] = {Wl[L], WlT[L], Kdim[L], Mdim[L], off};
      off += Kdim[L] * Mdim[L];
      ta.d[2 * L + 1] = {Wr[L], WrT[L], Kdim[L], Mdim[L], off};
      off += Kdim[L] * Mdim[L];
    }
    ta.total = off;
    transpose_all_kernel<<<(ta.total + 255) / 256, 256, 0, stream>>>(ta);
  }

  // ---- layer-0 input fp32 -> fp16 ----
  cvt_half_kernel<<<1024, 256, 0, stream>>>(n_feat, A0, N * 512);

  // ---- CSR by dst ----
  hipMemsetAsync(counts, 0, (size_t)N * sizeof(int), stream);
  hist_kernel<<<(E + 255) / 256, 256, 0, stream>>>(dst, counts, E);
  scan_kernel<<<1, 256, 0, stream>>>(counts, rowptr, cursor, N);
  scatter_kernel<<<(E + 255) / 256, 256, 0, stream>>>(src, dst, cursor, csrc,
                                                      E);

  const _Float16* Ain[3] = {A0, h1, h2};

  const int nStrips = (N + TM - 1) / TM;   // 157
  const int S8 = ((nStrips + 7) / 8) * 8;  // 160

  for (int L = 0; L < 3; ++L) {
    const int K = Kdim[L], M = Mdim[L];
    const int nbx = 2 * M / TN;  // 8 or 4
    const int nbxLog2 = (nbx == 8) ? 3 : 2;
    gemm_mfma_dual_kernel<<<S8 * nbx, 256, 0, stream>>>(
        Ain[L], WlT[L], WrT[L], fs, fd, N, K, M, nStrips, nbxLog2);
    if (L == 0) {
      node_attn_kernel<128><<<(N + 3) / 4, 256, 0, stream>>>(
          fs, fd, rowptr, csrc, attn[L], bias[L], nullptr, h1, N);
    } else if (L == 1) {
      node_attn_kernel<128><<<(N + 3) / 4, 256, 0, stream>>>(
          fs, fd, rowptr, csrc, attn[L], bias[L], nullptr, h2, N);
    } else {
      node_attn_kernel<64><<<(N + 3) / 4, 256, 0, stream>>>(
          fs, fd, rowptr, csrc, attn[L], bias[L], hfin, nullptr, N);
    }
  }

  hipMemsetAsync(d_out, 0, 64 * sizeof(float), stream);
  final_mean_kernel<<<256, 64, 0, stream>>>(hfin, (float*)d_out, N);
}

// Round 8
// 412.241 us; speedup vs baseline: 7.5252x; 1.0811x over previous
//
#include <hip/hip_runtime.h>
#include <hip/hip_bf16.h>
#include <stdint.h>

// GATv2 3-layer network. Round 7: packed-fp16 attn hot loop (v_pk_* + 
// v_dot2_f32_f16 logits, v_fma_mix O-update), fused preproc kernel.
// Keeps: fp16 MFMA dual GEMM w/ XCD swizzle + global_load_lds, CSR attn x4.

#define GAT_SLOPE 0.2f
#define ACT_SLOPE 0.01f

typedef _Float16 half8 __attribute__((ext_vector_type(8)));
typedef _Float16 v2h __attribute__((ext_vector_type(2)));
typedef float floatx4 __attribute__((ext_vector_type(4)));

// ---------------- fused preprocessing ----------------
// One kernel: (1) 6 weight transposes fp32->fp16 [M][K], (2) layer-0 input
// fp32->fp16, (3) dst histogram for CSR.
struct TransDesc {
  const float* src;
  _Float16* dst;
  int K, M, off;
};
struct PreArgs {
  TransDesc d[6];
  int wTotal;
  const float* nf;
  _Float16* A0;
  int aTotal;
  const int* dst;
  int* counts;
  int E;
};

__global__ __launch_bounds__(256) void preproc_kernel(PreArgs pa) {
  int i = blockIdx.x * 256 + threadIdx.x;
  const int total = pa.wTotal + pa.aTotal + pa.E;
  if (i >= total) return;
  if (i < pa.wTotal) {
    int q = 0;
#pragma unroll
    for (int j = 1; j < 6; ++j)
      if (i >= pa.d[j].off) q = j;
    int local = i - pa.d[q].off;
    int K = pa.d[q].K, M = pa.d[q].M;
    int k = local / M, m = local % M;
    pa.d[q].dst[(size_t)m * K + k] = (_Float16)pa.d[q].src[local];
  } else if (i < pa.wTotal + pa.aTotal) {
    int j = i - pa.wTotal;
    pa.A0[j] = (_Float16)pa.nf[j];
  } else {
    int e = i - pa.wTotal - pa.aTotal;
    atomicAdd(&pa.counts[pa.dst[e]], 1);
  }
}

// ---------------- async global -> LDS (16B per lane) ----------------
__device__ __forceinline__ void gload_lds16(const _Float16* g, _Float16* l) {
  __builtin_amdgcn_global_load_lds(
      (__attribute__((address_space(1))) unsigned int*)g,
      (__attribute__((address_space(3))) unsigned int*)l, 16, 0, 0);
}

// ---------------- fp16 MFMA GEMM, dual-B, fp16 output ----------------
#define TM 128
#define TN 128
#define TK 32

__global__ __launch_bounds__(256) void gemm_mfma_dual_kernel(
    const _Float16* __restrict__ A, const _Float16* __restrict__ B0,
    const _Float16* __restrict__ B1, _Float16* __restrict__ C0,
    _Float16* __restrict__ C1, int Nrow, int K, int M, int nStrips,
    int nbxLog2) {
  const int id = blockIdx.x;
  const int xcd = id & 7;
  const int s = id >> 3;
  const int nbx = 1 << nbxLog2;
  const int col = s & (nbx - 1);
  const int chunk = s >> nbxLog2;
  const int strip = chunk * 8 + xcd;
  if (strip >= nStrips) return;

  const int nb = nbx >> 1;
  const bool second = col >= nb;
  const _Float16* B = second ? B1 : B0;
  _Float16* C = second ? C1 : C0;
  const int bn = (second ? col - nb : col) * TN;
  const int bm = strip * TM;

  __shared__ __align__(16) _Float16 As[TM * TK];
  __shared__ __align__(16) _Float16 Bs[TN * TK];

  const int tid = threadIdx.x;
  const int w = tid >> 6;
  const int lane = tid & 63;
  const int wr = w >> 1;
  const int wc = w & 1;
  const int quad = lane >> 4;
  const int lr = lane & 15;

  const int lrow = lane >> 2;
  const int loff = (lane & 3) * 8;

  floatx4 acc[4][4];
#pragma unroll
  for (int i = 0; i < 4; ++i)
#pragma unroll
    for (int j = 0; j < 4; ++j) acc[i][j] = (floatx4){0.f, 0.f, 0.f, 0.f};

  const int KT = K / TK;
  for (int kt = 0; kt < KT; ++kt) {
    const int k0 = kt * TK;
#pragma unroll
    for (int half = 0; half < 2; ++half) {
      const int r0 = w * 32 + half * 16;
      int ga = bm + r0 + lrow;
      if (ga >= Nrow) ga = Nrow - 1;
      gload_lds16(A + (size_t)ga * K + k0 + loff, As + r0 * TK);
      gload_lds16(B + (size_t)(bn + r0 + lrow) * K + k0 + loff, Bs + r0 * TK);
    }
    __syncthreads();

    half8 ar[4], br[4];
#pragma unroll
    for (int i = 0; i < 4; ++i) {
      int row = wr * 64 + i * 16 + lr;
      ar[i] = *(const half8*)(As + row * TK + quad * 8);
    }
#pragma unroll
    for (int j = 0; j < 4; ++j) {
      int colr = wc * 64 + j * 16 + lr;
      br[j] = *(const half8*)(Bs + colr * TK + quad * 8);
    }
#pragma unroll
    for (int i = 0; i < 4; ++i)
#pragma unroll
      for (int j = 0; j < 4; ++j)
        acc[i][j] = __builtin_amdgcn_mfma_f32_16x16x32_f16(ar[i], br[j],
                                                           acc[i][j], 0, 0, 0);
    __syncthreads();
  }

#pragma unroll
  for (int i = 0; i < 4; ++i) {
#pragma unroll
    for (int r = 0; r < 4; ++r) {
      int row = bm + wr * 64 + i * 16 + quad * 4 + r;
      if (row >= Nrow) continue;
#pragma unroll
      for (int j = 0; j < 4; ++j) {
        int colc = bn + wc * 64 + j * 16 + lr;
        C[(size_t)row * M + colc] = (_Float16)acc[i][j][r];
      }
    }
  }
}

// ---------------- CSR scan + scatter ----------------
__global__ __launch_bounds__(256) void scan_kernel(
    const int* __restrict__ counts, int* __restrict__ rowptr,
    int* __restrict__ cursor, int N) {
  __shared__ int sums[256];
  const int t = threadIdx.x;
  const int C = (N + 255) / 256;
  const int lo = t * C;
  const int hi = min(lo + C, N);
  int s = 0;
  for (int i = lo; i < hi; ++i) s += counts[i];
  sums[t] = s;
  __syncthreads();
  for (int off = 1; off < 256; off <<= 1) {
    int v = (t >= off) ? sums[t - off] : 0;
    __syncthreads();
    sums[t] += v;
    __syncthreads();
  }
  int run = (t == 0) ? 0 : sums[t - 1];
  for (int i = lo; i < hi; ++i) {
    rowptr[i] = run;
    cursor[i] = run;
    run += counts[i];
  }
  if (t == 255) rowptr[N] = run;
}

__global__ __launch_bounds__(256) void scatter_kernel(
    const int* __restrict__ src, const int* __restrict__ dst,
    int* __restrict__ cursor, int* __restrict__ csrc, int E) {
  int e = blockIdx.x * 256 + threadIdx.x;
  if (e < E) {
    int p = atomicAdd(&cursor[dst[e]], 1);
    csrc[p] = src[e];
  }
}

// ---------------- fused per-node GATv2 attention (packed fp16) ----------
// One wave per dst node, 4 nodes/block, edge loop unrolled x4.
// Logits: v_pk_add/max + v_dot2_f32_f16 (fp32 accum). O-update: fma_mix.
template <int D>
__global__ __launch_bounds__(256) void node_attn_kernel(
    const _Float16* __restrict__ fs, const _Float16* __restrict__ fd,
    const int* __restrict__ rowptr, const int* __restrict__ csrc,
    const float* __restrict__ attn, const float* __restrict__ bias,
    float* __restrict__ hout, _Float16* __restrict__ oh, int N) {
  constexpr int HD = 4 * D;
  constexpr int R = HD / 64;
  constexpr int R2 = R / 2;
  typedef _Float16 halfR __attribute__((ext_vector_type(R)));
  union Frag {
    halfR v;
    v2h h[R2];
    _Float16 s[R];
  };
  const int v = blockIdx.x * 4 + (threadIdx.x >> 6);
  if (v >= N) return;
  const int lane = threadIdx.x & 63;

  const v2h slope2 = {(_Float16)GAT_SLOPE, (_Float16)GAT_SLOPE};

  Frag fdv;
  fdv.v = *(const halfR*)(fd + (size_t)v * HD + lane * R);
  v2h ar2[R2];
#pragma unroll
  for (int j = 0; j < R2; ++j) {
    ar2[j][0] = (_Float16)attn[lane * R + 2 * j];
    ar2[j][1] = (_Float16)attn[lane * R + 2 * j + 1];
  }

  float m = -INFINITY, l = 0.f;
  float O[R];
#pragma unroll
  for (int i = 0; i < R; ++i) O[i] = 0.f;

  const int e0 = rowptr[v];
  const int e1 = rowptr[v + 1];
  int k = e0;
  for (; k + 3 < e1; k += 4) {
    const int s0 = csrc[k];
    const int s1 = csrc[k + 1];
    const int s2 = csrc[k + 2];
    const int s3 = csrc[k + 3];
    Frag t0, t1, t2, t3;
    t0.v = *(const halfR*)(fs + (size_t)s0 * HD + lane * R);
    t1.v = *(const halfR*)(fs + (size_t)s1 * HD + lane * R);
    t2.v = *(const halfR*)(fs + (size_t)s2 * HD + lane * R);
    t3.v = *(const halfR*)(fs + (size_t)s3 * HD + lane * R);
    float p0 = 0.f, p1 = 0.f, p2 = 0.f, p3 = 0.f;
#pragma unroll
    for (int j = 0; j < R2; ++j) {
      v2h x0 = t0.h[j] + fdv.h[j];
      v2h x1 = t1.h[j] + fdv.h[j];
      v2h x2 = t2.h[j] + fdv.h[j];
      v2h x3 = t3.h[j] + fdv.h[j];
      x0 = __builtin_elementwise_max(x0, x0 * slope2);
      x1 = __builtin_elementwise_max(x1, x1 * slope2);
      x2 = __builtin_elementwise_max(x2, x2 * slope2);
      x3 = __builtin_elementwise_max(x3, x3 * slope2);
      p0 = __builtin_amdgcn_fdot2(ar2[j], x0, p0, false);
      p1 = __builtin_amdgcn_fdot2(ar2[j], x1, p1, false);
      p2 = __builtin_amdgcn_fdot2(ar2[j], x2, p2, false);
      p3 = __builtin_amdgcn_fdot2(ar2[j], x3, p3, false);
    }
#pragma unroll
    for (int off = 1; off <= 8; off <<= 1) {
      p0 += __shfl_xor(p0, off, 64);
      p1 += __shfl_xor(p1, off, 64);
      p2 += __shfl_xor(p2, off, 64);
      p3 += __shfl_xor(p3, off, 64);
    }
    const float mq = fmaxf(fmaxf(p0, p1), fmaxf(p2, p3));
    const float w0 = __expf(p0 - mq);
    const float w1 = __expf(p1 - mq);
    const float w2 = __expf(p2 - mq);
    const float w3 = __expf(p3 - mq);
    const float mnew = fmaxf(m, mq);
    const float sc = __expf(m - mnew);
    const float sq = __expf(mq - mnew);
    l = l * sc + (w0 + w1 + w2 + w3) * sq;
#pragma unroll
    for (int i = 0; i < R; ++i) {
      float acc = (float)t0.s[i] * w0;           // v_fma_mix chain
      acc = fmaf((float)t1.s[i], w1, acc);
      acc = fmaf((float)t2.s[i], w2, acc);
      acc = fmaf((float)t3.s[i], w3, acc);
      O[i] = fmaf(O[i], sc, sq * acc);
    }
    m = mnew;
  }
  for (; k < e1; ++k) {
    const int s0 = csrc[k];
    Frag t0;
    t0.v = *(const halfR*)(fs + (size_t)s0 * HD + lane * R);
    float p0 = 0.f;
#pragma unroll
    for (int j = 0; j < R2; ++j) {
      v2h x0 = t0.h[j] + fdv.h[j];
      x0 = __builtin_elementwise_max(x0, x0 * slope2);
      p0 = __builtin_amdgcn_fdot2(ar2[j], x0, p0, false);
    }
#pragma unroll
    for (int off = 1; off <= 8; off <<= 1) p0 += __shfl_xor(p0, off, 64);
    const float mnew = fmaxf(m, p0);
    const float sc = __expf(m - mnew);
    const float p = __expf(p0 - mnew);
    l = l * sc + p;
#pragma unroll
    for (int i = 0; i < R; ++i)
      O[i] = fmaf(O[i], sc, p * (float)t0.s[i]);
    m = mnew;
  }

  const float inv = (l > 0.f) ? 1.f / l : 0.f;
#pragma unroll
  for (int i = 0; i < R; ++i) O[i] = O[i] * inv + bias[lane * R + i];
#pragma unroll
  for (int i = 0; i < R; ++i) {
    O[i] += __shfl_xor(O[i], 16, 64);
    O[i] += __shfl_xor(O[i], 32, 64);
    float x = O[i] * 0.25f;
    O[i] = x > 0.f ? x : x * ACT_SLOPE;
  }
  if (lane < 16) {
    const size_t base = (size_t)v * D + lane * R;
    if (hout) {
#pragma unroll
      for (int i = 0; i < R; ++i) hout[base + i] = O[i];
    }
    if (oh) {
#pragma unroll
      for (int i = 0; i < R; ++i) oh[base + i] = (_Float16)O[i];
    }
  }
}

// ------------- out[d] = mean_n h[n,d] -------------
__global__ __launch_bounds__(64) void final_mean_kernel(
    const float* __restrict__ h, float* __restrict__ out, int N) {
  const int d = threadIdx.x;
  float acc = 0.f;
  for (int n = blockIdx.x; n < N; n += gridDim.x) acc += h[(size_t)n * 64 + d];
  atomicAdd(&out[d], acc / (float)N);
}

// ------------------------------------------------------------------
extern "C" void kernel_launch(void* const* d_in, const int* in_sizes, int n_in,
                              void* d_out, int out_size, void* d_ws,
                              size_t ws_size, hipStream_t stream) {
  const float* n_feat = (const float*)d_in[0];
  const int* src = (const int*)d_in[1];
  const int* dst = (const int*)d_in[2];
  const float* Wl[3] = {(const float*)d_in[3], (const float*)d_in[7],
                        (const float*)d_in[11]};
  const float* Wr[3] = {(const float*)d_in[4], (const float*)d_in[8],
                        (const float*)d_in[12]};
  const float* attn[3] = {(const float*)d_in[5], (const float*)d_in[9],
                          (const float*)d_in[13]};
  const float* bias[3] = {(const float*)d_in[6], (const float*)d_in[10],
                          (const float*)d_in[14]};

  const int N = in_sizes[0] / 512;  // 20000
  const int E = in_sizes[1];        // 320000
  const int Kdim[3] = {512, 128, 128};
  const int Mdim[3] = {512, 512, 256};

  char* ws = (char*)d_ws;
  size_t o = 0;
  auto alloc = [&](size_t bytes) {
    void* p = ws + o;
    o += (bytes + 15) & ~(size_t)15;
    return p;
  };
  _Float16* fs = (_Float16*)alloc((size_t)N * 512 * 2);
  _Float16* fd = (_Float16*)alloc((size_t)N * 512 * 2);
  _Float16* A0 = (_Float16*)alloc((size_t)N * 512 * 2);
  _Float16* h1 = (_Float16*)alloc((size_t)N * 128 * 2);
  _Float16* h2 = (_Float16*)alloc((size_t)N * 128 * 2);
  float* hfin = (float*)alloc((size_t)N * 64 * 4);
  _Float16 *WlT[3], *WrT[3];
  for (int L = 0; L < 3; ++L) {
    size_t sz = (size_t)Kdim[L] * Mdim[L] * 2;
    WlT[L] = (_Float16*)alloc(sz);
    WrT[L] = (_Float16*)alloc(sz);
  }
  int* counts = (int*)alloc((size_t)N * 4);
  int* rowptr = (int*)alloc((size_t)(N + 1) * 4);
  int* cursor = (int*)alloc((size_t)N * 4);
  int* csrc = (int*)alloc((size_t)E * 4);

  // ---- fused preprocessing: weight transposes + A0 cvt + dst histogram ----
  hipMemsetAsync(counts, 0, (size_t)N * sizeof(int), stream);
  {
    PreArgs pa;
    int off = 0;
    for (int L = 0; L < 3; ++L) {
      pa.d[2 * L] = {Wl[L], WlT[L], Kdim[L], Mdim[L], off};
      off += Kdim[L] * Mdim[L];
      pa.d[2 * L + 1] = {Wr[L], WrT[L], Kdim[L], Mdim[L], off};
      off += Kdim[L] * Mdim[L];
    }
    pa.wTotal = off;
    pa.nf = n_feat;
    pa.A0 = A0;
    pa.aTotal = N * 512;
    pa.dst = dst;
    pa.counts = counts;
    pa.E = E;
    int total = pa.wTotal + pa.aTotal + pa.E;
    preproc_kernel<<<(total + 255) / 256, 256, 0, stream>>>(pa);
  }
  scan_kernel<<<1, 256, 0, stream>>>(counts, rowptr, cursor, N);
  scatter_kernel<<<(E + 255) / 256, 256, 0, stream>>>(src, dst, cursor, csrc,
                                                      E);

  const _Float16* Ain[3] = {A0, h1, h2};

  const int nStrips = (N + TM - 1) / TM;   // 157
  const int S8 = ((nStrips + 7) / 8) * 8;  // 160

  for (int L = 0; L < 3; ++L) {
    const int K = Kdim[L], M = Mdim[L];
    const int nbx = 2 * M / TN;  // 8 or 4
    const int nbxLog2 = (nbx == 8) ? 3 : 2;
    gemm_mfma_dual_kernel<<<S8 * nbx, 256, 0, stream>>>(
        Ain[L], WlT[L], WrT[L], fs, fd, N, K, M, nStrips, nbxLog2);
    if (L == 0) {
      node_attn_kernel<128><<<(N + 3) / 4, 256, 0, stream>>>(
          fs, fd, rowptr, csrc, attn[L], bias[L], nullptr, h1, N);
    } else if (L == 1) {
      node_attn_kernel<128><<<(N + 3) / 4, 256, 0, stream>>>(
          fs, fd, rowptr, csrc, attn[L], bias[L], nullptr, h2, N);
    } else {
      node_attn_kernel<64><<<(N + 3) / 4, 256, 0, stream>>>(
          fs, fd, rowptr, csrc, attn[L], bias[L], hfin, nullptr, N);
    }
  }

  hipMemsetAsync(d_out, 0, 64 * sizeof(float), stream);
  final_mean_kernel<<<256, 64, 0, stream>>>(hfin, (float*)d_out, N);
}